// Round 9
// baseline (433.714 us; speedup 1.0000x reference)
//
#include <hip/hip_runtime.h>
#include <hip/hip_bf16.h>
#include <cstdint>
#include <cstddef>

typedef __bf16 bf16;
typedef __bf16 bf16x2 __attribute__((ext_vector_type(2)));
typedef __bf16 bf16x8 __attribute__((ext_vector_type(8)));
typedef float  f32x4  __attribute__((ext_vector_type(4)));

#define HIDDEN 2048
#define NHEADS 16
#define NKV    4
#define HD     128
#define WINDOW 512

// async global->LDS, 16B per lane; LDS dest is wave-uniform base + lane*16
__device__ __forceinline__ void gld16(const void* g, void* s) {
  __builtin_amdgcn_global_load_lds((const __attribute__((address_space(1))) void*)g,
                                   (__attribute__((address_space(3))) void*)s, 16, 0, 0);
}

__device__ __forceinline__ f32x4 mfma16(bf16x8 a, bf16x8 b, f32x4 c) {
  return __builtin_amdgcn_mfma_f32_16x16x32_bf16(a, b, c, 0, 0, 0);
}

__device__ __forceinline__ void barrier_raw() {
  asm volatile("" ::: "memory");
  __builtin_amdgcn_s_barrier();
  asm volatile("" ::: "memory");
}

// ---------------- cast fp32 -> bf16, 4 elems/thread -------------------------
__global__ __launch_bounds__(256) void cast_f32_bf16(const float* __restrict__ in,
                                                     bf16* __restrict__ out, int n4) {
  int i = blockIdx.x * 256 + threadIdx.x;
  if (i >= n4) return;
  f32x4 v = *(const f32x4*)(in + (size_t)i * 4);
  bf16x2 a, b;
  a[0] = (bf16)v[0]; a[1] = (bf16)v[1];
  b[0] = (bf16)v[2]; b[1] = (bf16)v[3];
  *(bf16x2*)(out + (size_t)i * 4)     = a;
  *(bf16x2*)(out + (size_t)i * 4 + 2) = b;
}

// ---------------- transpose+cast: fp32 (R x C) -> bf16 (C x R) --------------
__global__ __launch_bounds__(256) void transpose_cast(const float* __restrict__ in,
                                                      bf16* __restrict__ out, int R, int C) {
  __shared__ float tile[32][33];
  int c0 = blockIdx.x * 32, r0 = blockIdx.y * 32;
  int tx = threadIdx.x, ty = threadIdx.y;
  #pragma unroll
  for (int i = 0; i < 4; ++i)
    tile[ty + i * 8][tx] = in[(size_t)(r0 + ty + i * 8) * C + c0 + tx];
  __syncthreads();
  #pragma unroll
  for (int i = 0; i < 4; ++i)
    out[(size_t)(c0 + ty + i * 8) * R + r0 + tx] = (bf16)tile[tx][ty + i * 8];
}

// ========== 128x128 GEMM (merged K+V projection, outMode 3 splits) ==========
__device__ __forceinline__ void stage128x32(const bf16* __restrict__ A,
                                            const bf16* __restrict__ Bt,
                                            bf16* sA, bf16* sB,
                                            int m0, int n0, int K, int kt, int tid) {
  int wbase = tid & ~63;
  #pragma unroll
  for (int r = 0; r < 2; ++r) {
    int e = (r * 256 + tid) * 8;
    int row = e >> 5, col = e & 31;
    gld16(A  + (size_t)(m0 + row) * K + (size_t)kt * 32 + col,
          sA + (size_t)(r * 256 + wbase) * 8);
    gld16(Bt + (size_t)(n0 + row) * K + (size_t)kt * 32 + col,
          sB + (size_t)(r * 256 + wbase) * 8);
  }
}

// outMode: 0 bf16 row-major; 1 bf16 C^T; 2 fp32 row-major;
//          3 merged KV: col<512 -> Cv row-major (N=512), col>=512 -> Vt^T
__global__ __launch_bounds__(256) void gemm_bt(const bf16* __restrict__ A,
                                               const bf16* __restrict__ Bt,
                                               void* __restrict__ Cv,
                                               bf16* __restrict__ Vtout,
                                               int M, int N, int K, int outMode) {
  __shared__ bf16 sA[2][128 * 32];
  __shared__ bf16 sB[2][128 * 32];
  int nb = N >> 7;
  int bm = (int)blockIdx.x / nb, bn = (int)blockIdx.x % nb;
  int m0 = bm << 7, n0 = bn << 7;
  int tid = threadIdx.x;
  int lane = tid & 63, w = tid >> 6;
  int li = lane & 15, g = lane >> 4, g8 = g * 8;
  int wm = w >> 1, wn = w & 1;
  f32x4 acc[4][4] = {};
  int NT = K >> 5;

  stage128x32(A, Bt, sA[0], sB[0], m0, n0, K, 0, tid);
  __syncthreads();
  for (int kt = 0; kt < NT; ++kt) {
    int cur = kt & 1;
    if (kt + 1 < NT)
      stage128x32(A, Bt, sA[cur ^ 1], sB[cur ^ 1], m0, n0, K, kt + 1, tid);
    bf16x8 af[4], bv[4];
    #pragma unroll
    for (int mt = 0; mt < 4; ++mt)
      af[mt] = *(const bf16x8*)&sA[cur][(wm * 64 + mt * 16 + li) * 32 + g8];
    #pragma unroll
    for (int nt = 0; nt < 4; ++nt)
      bv[nt] = *(const bf16x8*)&sB[cur][(wn * 64 + nt * 16 + li) * 32 + g8];
    #pragma unroll
    for (int mt = 0; mt < 4; ++mt)
      #pragma unroll
      for (int nt = 0; nt < 4; ++nt)
        acc[mt][nt] = mfma16(af[mt], bv[nt], acc[mt][nt]);
    __syncthreads();
  }
  #pragma unroll
  for (int mt = 0; mt < 4; ++mt)
    #pragma unroll
    for (int nt = 0; nt < 4; ++nt)
      #pragma unroll
      for (int j = 0; j < 4; ++j) {
        int row = m0 + wm * 64 + mt * 16 + g * 4 + j;
        int col = n0 + wn * 64 + nt * 16 + li;
        float v = acc[mt][nt][j];
        if (outMode == 0)      ((bf16*)Cv)[(size_t)row * N + col] = (bf16)v;
        else if (outMode == 1) ((bf16*)Cv)[(size_t)col * M + row] = (bf16)v;
        else if (outMode == 2) ((float*)Cv)[(size_t)row * N + col] = v;
        else {  // 3: merged KV
          if (col < 512) ((bf16*)Cv)[(size_t)row * 512 + col] = (bf16)v;
          else           Vtout[(size_t)(col - 512) * M + row] = (bf16)v;
        }
      }
}

// ============ 256x256 GEMM, 16 waves (4x4), 8-phase counted-vmcnt ===========
// BM=BN=256, BK=64, 1024 threads. Wave tile 64x64 (acc 4x4 f32x4 = 64 VGPR).
// Halves are bit5-row-granules (RSP=32 for A AND B): quadrant (mh,nh) reads
// rows with bit5==mh / bit5==nh only -> stage-overwrite hazards are phase-
// disjoint. Per K-tile 4 phases (quadrant zigzag 00->01->11->10); 2 K-tiles
// per iteration (buf0/buf1). One stage (1 gld16/thread, 16KB) per phase.
// vmcnt gating: VMW(3) BEFORE the closing barrier of p3/p7 so that the
// barrier publishes ALL waves' completed stages before any ds_read of the
// gated tile (per-wave vmcnt + barrier = cross-wave visibility).
// Stage slots (region last ds_read >= 1 barrier before stage issue):
//  p0:A1(2i+1)[A1 buf1 read p6' prev]  p1:A0(2i+2)[read p0]  p2:B0(2i+2)[p0]
//  p3:B1(2i+2)[p1]  p4:A1(2i+2)[p2]  p5:A0(2i+3)[p4]  p6:B0(2i+3)[p4]
//  p7:B1(2i+3)[p5]
template<int RSP>
__device__ __forceinline__ void stage_h16(const bf16* __restrict__ G,
                                          bf16* __restrict__ sbuf,
                                          int grow0, int K, int k0, int half, int tid) {
  int w = tid >> 6, lane = tid & 63;
  int rl = lane >> 3;                         // row within 8-row group
  int col = ((lane & 7) ^ rl) * 8;            // inverse-swizzled SOURCE col (rule #21)
  int lr0 = w * 8;                            // 0..120
  int row0 = (lr0 & (RSP - 1)) + half * RSP + (lr0 / RSP) * 2 * RSP;
  gld16(G + (size_t)(grow0 + row0 + rl) * K + k0 + col,
        sbuf + row0 * 64);                    // wave-uniform linear LDS dest
}

// outMode: 0 = bf16 row-major; 2 = fp32 row-major
__global__ __launch_bounds__(1024) void gemm256(const bf16* __restrict__ A,
                                                const bf16* __restrict__ Bt,
                                                void* __restrict__ Cv,
                                                int M, int N, int K, int outMode) {
  __shared__ bf16 sA[2][256 * 64];
  __shared__ bf16 sB[2][256 * 64];
  int nb = N >> 8;
  int cpx = (int)gridDim.x >> 3;
  int bid = (int)blockIdx.x;
  int swzb = (bid & 7) * cpx + (bid >> 3);
  int bm = swzb / nb, bn = swzb % nb;
  int m0 = bm << 8, n0 = bn << 8;
  int tid = threadIdx.x, lane = tid & 63, w = tid >> 6;
  int li = lane & 15, g = lane >> 4;
  int wm = w >> 2, wn = w & 3;                // 4 x 4 wave grid
  int swz = li & 7;

  f32x4 acc[4][4] = {};
  bf16x8 af[2][2];       // A frags, current mh
  bf16x8 bv[2][2][2];    // B frags, both nh (bv[0] reused at p3/p7)

  int NT = K >> 6;       // 32
  int NI = NT >> 1;

  // prologue: tile0 {A0,B0,B1,A1}, tile1 {A0,B0,B1}; A1(t1) staged at p0.
  stage_h16<32>(A,  sA[0], m0, K, 0,  0, tid);
  stage_h16<32>(Bt, sB[0], n0, K, 0,  0, tid);
  stage_h16<32>(Bt, sB[0], n0, K, 0,  1, tid);
  stage_h16<32>(A,  sA[0], m0, K, 0,  1, tid);
  stage_h16<32>(A,  sA[1], m0, K, 64, 0, tid);
  stage_h16<32>(Bt, sB[1], n0, K, 64, 0, tid);
  stage_h16<32>(Bt, sB[1], n0, K, 64, 1, tid);

#define VMW(n) asm volatile("s_waitcnt vmcnt(" #n ")" ::: "memory")
#define LGKM0() { asm volatile("s_waitcnt lgkmcnt(0)" ::: "memory"); \
  __builtin_amdgcn_sched_barrier(0); }
#define LOAD_A(mh, bi) { _Pragma("unroll") for (int mf = 0; mf < 2; ++mf) \
  _Pragma("unroll") for (int ks = 0; ks < 2; ++ks) { \
    int row = wm * 64 + (mh) * 32 + mf * 16 + li; \
    af[mf][ks] = *(const bf16x8*)&sA[bi][row * 64 + ((ks * 4 + g) ^ swz) * 8]; } }
#define LOAD_B(nh, bi) { _Pragma("unroll") for (int nf = 0; nf < 2; ++nf) \
  _Pragma("unroll") for (int ks = 0; ks < 2; ++ks) { \
    int row = wn * 64 + (nh) * 32 + nf * 16 + li; \
    bv[nh][nf][ks] = *(const bf16x8*)&sB[bi][row * 64 + ((ks * 4 + g) ^ swz) * 8]; } }
#define MFMA_PH(mh, nh) { \
  __builtin_amdgcn_s_setprio(1); \
  _Pragma("unroll") for (int mf = 0; mf < 2; ++mf) \
  _Pragma("unroll") for (int nf = 0; nf < 2; ++nf) \
  _Pragma("unroll") for (int ks = 0; ks < 2; ++ks) \
    acc[(mh) * 2 + mf][(nh) * 2 + nf] = \
      mfma16(af[mf][ks], bv[nh][nf][ks], acc[(mh) * 2 + mf][(nh) * 2 + nf]); \
  __builtin_amdgcn_s_setprio(0); }

  // gate tile0 (first 4 stages): own loads <=3 outstanding, then publish.
  VMW(3);
  barrier_raw();

  for (int i = 0; i < NI; ++i) {
    const int kA1c = (2 * i + 1) << 6;       // A1 of tile 2i+1 (buf1)
    const int kN2  = (2 * i + 2) << 6;
    const int kN3  = (2 * i + 3) << 6;
    const bool pre = (i + 1 < NI);
    // ---- p0: quad(0,0) buf0 ----
    LOAD_A(0, 0); LOAD_B(0, 0);                               // 8 ds_read
    stage_h16<32>(A, sA[1], m0, K, kA1c, 1, tid);             // A1(2i+1)
    barrier_raw(); LGKM0();
    MFMA_PH(0, 0);
    barrier_raw();
    // ---- p1: quad(0,1) ----
    LOAD_B(1, 0);                                             // 4 ds_read
    if (pre) stage_h16<32>(A, sA[0], m0, K, kN2, 0, tid);     // A0(2i+2)
    barrier_raw(); LGKM0();
    MFMA_PH(0, 1);
    barrier_raw();
    // ---- p2: quad(1,1) ----
    LOAD_A(1, 0);                                             // 4 ds_read
    if (pre) stage_h16<32>(Bt, sB[0], n0, K, kN2, 0, tid);    // B0(2i+2)
    barrier_raw(); LGKM0();
    MFMA_PH(1, 1);
    barrier_raw();
    // ---- p3: quad(1,0); gate tile 2i+1 (VMW before publishing barrier) ----
    if (pre) { stage_h16<32>(Bt, sB[0], n0, K, kN2, 1, tid); VMW(3); }  // B1(2i+2)
    else     { VMW(0); }
    barrier_raw();
    MFMA_PH(1, 0);
    barrier_raw();
    // ---- p4: quad(0,0) buf1 ----
    LOAD_A(0, 1); LOAD_B(0, 1);                               // 8 ds_read
    if (pre) stage_h16<32>(A, sA[0], m0, K, kN2, 1, tid);     // A1(2i+2)
    barrier_raw(); LGKM0();
    MFMA_PH(0, 0);
    barrier_raw();
    // ---- p5: quad(0,1) ----
    LOAD_B(1, 1);                                             // 4 ds_read
    if (pre) stage_h16<32>(A, sA[1], m0, K, kN3, 0, tid);     // A0(2i+3)
    barrier_raw(); LGKM0();
    MFMA_PH(0, 1);
    barrier_raw();
    // ---- p6: quad(1,1) ----
    LOAD_A(1, 1);                                             // 4 ds_read
    if (pre) stage_h16<32>(Bt, sB[1], n0, K, kN3, 0, tid);    // B0(2i+3)
    barrier_raw(); LGKM0();
    MFMA_PH(1, 1);
    barrier_raw();
    // ---- p7: quad(1,0); gate tile 2i+2 ----
    if (pre) { stage_h16<32>(Bt, sB[1], n0, K, kN3, 1, tid); VMW(3); }  // B1(2i+3)
    barrier_raw();
    MFMA_PH(1, 0);
    barrier_raw();
  }
#undef VMW
#undef LGKM0
#undef LOAD_A
#undef LOAD_B
#undef MFMA_PH

  #pragma unroll
  for (int mi = 0; mi < 4; ++mi)
    #pragma unroll
    for (int ni = 0; ni < 4; ++ni)
      #pragma unroll
      for (int j = 0; j < 4; ++j) {
        int row = m0 + wm * 64 + mi * 16 + g * 4 + j;
        int col = n0 + wn * 64 + ni * 16 + li;
        float v = acc[mi][ni][j];
        if (outMode == 2) ((float*)Cv)[(size_t)row * N + col] = v;
        else              ((bf16*)Cv)[(size_t)row * N + col] = (bf16)v;
      }
}

// ---------------- RoPE in place: X (T x heads*128), interleaved pairs -------
__global__ __launch_bounds__(256) void rope_kernel(bf16* __restrict__ X,
                                                   const int* __restrict__ pos,
                                                   int T, int heads) {
  int idx = blockIdx.x * 256 + threadIdx.x;
  int total = T * heads * 64;
  if (idx >= total) return;
  int i = idx & 63;
  int rest = idx >> 6;
  int hh = rest % heads;
  int t = rest / heads;
  float inv = expf((float)i * (-9.210340371976184f / 64.0f)); // theta^(-i/64)
  float ang = (float)pos[t] * inv;
  float s, c;
  sincosf(ang, &s, &c);
  bf16* p = X + ((size_t)t * heads + hh) * HD + 2 * i;
  bf16x2 xv = *(const bf16x2*)p;
  float xe = (float)xv[0], xo = (float)xv[1];
  bf16x2 r;
  r[0] = (bf16)(xe * c - xo * s);
  r[1] = (bf16)(xe * s + xo * c);
  *(bf16x2*)p = r;
}

// ---------------- sliding-window GQA flash attention ------------------------
__global__ __launch_bounds__(256) void attn_kernel(const bf16* __restrict__ Q,
                                                   const bf16* __restrict__ Kb,
                                                   const bf16* __restrict__ Vt,
                                                   const int* __restrict__ pos,
                                                   const int* __restrict__ cu,
                                                   bf16* __restrict__ O, int T, int B) {
  __shared__ bf16 sK[32 * 128];    // data(row,chunk) stored at chunk^(row&7); 16B chunks
  __shared__ bf16 sVt2[64 * 64];   // LDS row r: d=2r (chunks 0-3), d=2r+1 (chunks 4-7), ^(r&7)
  __shared__ bf16 sP[4][16 * 40];  // per-wave P tile, stride 40 elems = conflict-free
  int bid = blockIdx.x;
  int h  = bid & (NHEADS - 1);
  int qb = bid >> 4;
  int q0 = qb * 64;
  int kvh = h >> 2;
  int tid = threadIdx.x, lane = tid & 63, w = tid >> 6;
  int li = lane & 15, g = lane >> 4, g8 = g * 8;
  int qw0 = q0 + w * 16;

  int seq_start = 0, seq_end = T;
  for (int b = 0; b < B; ++b) {
    int a = cu[b], e = cu[b + 1];
    if (q0 >= a && q0 < e) { seq_start = a; seq_end = e; }
  }

  bf16x8 qf[4];
  #pragma unroll
  for (int kd = 0; kd < 4; ++kd)
    qf[kd] = *(const bf16x8*)(Q + (size_t)(qw0 + li) * HIDDEN + h * HD + kd * 32 + g8);

  int pq[4];
  #pragma unroll
  for (int j = 0; j < 4; ++j) pq[j] = pos[qw0 + g * 4 + j];
  int pqw_min = pos[qw0], pqw_max = pos[qw0 + 15];

  float lsum[4] = {0.f, 0.f, 0.f, 0.f};
  f32x4 acc[8] = {};

  int kstart = q0 - WINDOW;
  if (kstart < seq_start) kstart = seq_start;
  int kend = q0 + 64;
  if (kend > seq_end) kend = seq_end;
  const float scale = 0.08838834764831845f;

  for (int kb = kstart; kb < kend; kb += 32) {
    int wbase = tid & ~63;
    #pragma unroll
    for (int r = 0; r < 2; ++r) {
      int n = r * 256 + tid;
      int krow = n >> 4, kc = (n & 15) ^ (krow & 7);
      gld16(Kb + (size_t)(kb + krow) * (NKV * HD) + kvh * HD + kc * 8,
            sK + (size_t)(r * 256 + wbase) * 8);
      int vr = n >> 3, vc = (n & 7) ^ (vr & 7);
      int vd = 2 * vr + (vc >> 2), vkey = (vc & 3) * 8;
      gld16(Vt + (size_t)(kvh * HD + vd) * T + kb + vkey,
            sVt2 + (size_t)(r * 256 + wbase) * 8);
    }
    __syncthreads();

    int pkf = pos[kb], pkl = pos[kb + 31];
    bool active = !(pkf > pqw_max || pkl < pqw_min - WINDOW);
    if (active) {
      f32x4 s0v = {0.f, 0.f, 0.f, 0.f}, s1v = {0.f, 0.f, 0.f, 0.f};
      #pragma unroll
      for (int kd = 0; kd < 4; ++kd) {
        int chunk = kd * 4 + g;
        int c0 = chunk ^ (li & 7);
        bf16x8 b0 = *(const bf16x8*)&sK[li * 128 + c0 * 8];
        bf16x8 b1 = *(const bf16x8*)&sK[(16 + li) * 128 + c0 * 8];
        s0v = mfma16(qf[kd], b0, s0v);
        s1v = mfma16(qf[kd], b1, s1v);
      }
      bool interior = (pkl <= pqw_min) && (pqw_max - pkf <= WINDOW);
      if (interior) {
        #pragma unroll
        for (int j = 0; j < 4; ++j) {
          float p0 = __expf(s0v[j] * scale);
          float p1 = __expf(s1v[j] * scale);
          lsum[j] += p0 + p1;
          sP[w][(g * 4 + j) * 40 + li]      = (bf16)p0;
          sP[w][(g * 4 + j) * 40 + 16 + li] = (bf16)p1;
        }
      } else {
        int pk0 = pos[kb + li], pk1 = pos[kb + 16 + li];
        #pragma unroll
        for (int j = 0; j < 4; ++j) {
          int d0 = pq[j] - pk0, d1 = pq[j] - pk1;
          float p0 = (d0 >= 0 && d0 <= WINDOW) ? __expf(s0v[j] * scale) : 0.f;
          float p1 = (d1 >= 0 && d1 <= WINDOW) ? __expf(s1v[j] * scale) : 0.f;
          lsum[j] += p0 + p1;
          sP[w][(g * 4 + j) * 40 + li]      = (bf16)p0;
          sP[w][(g * 4 + j) * 40 + 16 + li] = (bf16)p1;
        }
      }
      bf16x8 pa = *(const bf16x8*)&sP[w][li * 40 + g8];
      #pragma unroll
      for (int dt = 0; dt < 8; ++dt) {
        int d = dt * 16 + li;
        int vr = d >> 1;
        int vc = ((d & 1) * 4 + g) ^ (vr & 7);
        bf16x8 vf = *(const bf16x8*)&sVt2[vr * 64 + vc * 8];
        acc[dt] = mfma16(pa, vf, acc[dt]);
      }
    }
    __syncthreads();
  }

  #pragma unroll
  for (int j = 0; j < 4; ++j) {
    float rs = lsum[j];
    rs += __shfl_xor(rs, 1);
    rs += __shfl_xor(rs, 2);
    rs += __shfl_xor(rs, 4);
    rs += __shfl_xor(rs, 8);
    float invl = 1.0f / rs;
    size_t base = (size_t)(qw0 + g * 4 + j) * HIDDEN + h * HD;
    #pragma unroll
    for (int dt = 0; dt < 8; ++dt)
      O[base + dt * 16 + li] = (bf16)(acc[dt][j] * invl);
  }
}

// ---------------- launcher --------------------------------------------------
extern "C" void kernel_launch(void* const* d_in, const int* in_sizes, int n_in,
                              void* d_out, int out_size, void* d_ws, size_t ws_size,
                              hipStream_t stream) {
  const float* X  = (const float*)d_in[0];
  const float* qw = (const float*)d_in[1];
  const float* kw = (const float*)d_in[2];
  const float* vw = (const float*)d_in[3];
  const float* ow = (const float*)d_in[4];
  const int* pos = (const int*)d_in[5];
  const int* cu  = (const int*)d_in[6];
  int T = in_sizes[0] / HIDDEN;     // 8192
  int B = in_sizes[6] - 1;          // 4
  float* out = (float*)d_out;

  bf16* ws = (bf16*)d_ws;
  size_t off = 0;
  bf16* Xb    = ws + off; off += (size_t)T * HIDDEN;
  bf16* Qb    = ws + off; off += (size_t)T * HIDDEN;       // Q, then attn out
  bf16* Kb    = ws + off; off += (size_t)T * (NKV * HD);
  bf16* Vt    = ws + off; off += (size_t)T * (NKV * HD);
  bf16* qwT   = ws + off; off += (size_t)HIDDEN * HIDDEN;
  bf16* kvwT  = ws + off; off += (size_t)1024 * HIDDEN;    // [kwT; vwT] stacked
  bf16* owT   = ws + off; off += (size_t)HIDDEN * HIDDEN;

  cast_f32_bf16<<<(T * HIDDEN / 4 + 255) / 256, 256, 0, stream>>>(X, Xb, T * HIDDEN / 4);

  dim3 tb(32, 8);
  transpose_cast<<<dim3(HIDDEN / 32, HIDDEN / 32), tb, 0, stream>>>(qw, qwT, HIDDEN, HIDDEN);
  transpose_cast<<<dim3(512 / 32, HIDDEN / 32), tb, 0, stream>>>(kw, kvwT, HIDDEN, 512);
  transpose_cast<<<dim3(512 / 32, HIDDEN / 32), tb, 0, stream>>>(vw, kvwT + (size_t)512 * HIDDEN, HIDDEN, 512);
  transpose_cast<<<dim3(HIDDEN / 32, HIDDEN / 32), tb, 0, stream>>>(ow, owT, HIDDEN, HIDDEN);

  // Q-projection: 256x256 16-wave GEMM, grid 256
  gemm256<<<(T / 256) * (HIDDEN / 256), 1024, 0, stream>>>(Xb, qwT, Qb, T, HIDDEN, HIDDEN, 0);
  // merged K+V projection: 512 blocks (2 per CU), split epilogue
  gemm_bt<<<(T / 128) * (1024 / 128), 256, 0, stream>>>(Xb, kvwT, Kb, Vt, T, 1024, HIDDEN, 3);

  rope_kernel<<<(T * NHEADS * 64 + 255) / 256, 256, 0, stream>>>(Qb, pos, T, NHEADS);
  rope_kernel<<<(T * NKV * 64 + 255) / 256, 256, 0, stream>>>(Kb, pos, T, NKV);

  attn_kernel<<<(T / 64) * NHEADS, 256, 0, stream>>>(Qb, Kb, Vt, pos, cu, Qb, T, B);

  // O-projection (fp32 out), grid 256
  gemm256<<<(T / 256) * (HIDDEN / 256), 1024, 0, stream>>>(Qb, owT, out, T, HIDDEN, HIDDEN, 2);
}

// Round 10
// 406.054 us; speedup vs baseline: 1.0681x; 1.0681x over previous
//
#include <hip/hip_runtime.h>
#include <hip/hip_bf16.h>
#include <cstdint>
#include <cstddef>

typedef __bf16 bf16;
typedef __bf16 bf16x2 __attribute__((ext_vector_type(2)));
typedef __bf16 bf16x8 __attribute__((ext_vector_type(8)));
typedef float  f32x4  __attribute__((ext_vector_type(4)));

#define HIDDEN 2048
#define NHEADS 16
#define NKV    4
#define HD     128
#define WINDOW 512

// async global->LDS, 16B per lane; LDS dest is wave-uniform base + lane*16
__device__ __forceinline__ void gld16(const void* g, void* s) {
  __builtin_amdgcn_global_load_lds((const __attribute__((address_space(1))) void*)g,
                                   (__attribute__((address_space(3))) void*)s, 16, 0, 0);
}

__device__ __forceinline__ f32x4 mfma16(bf16x8 a, bf16x8 b, f32x4 c) {
  return __builtin_amdgcn_mfma_f32_16x16x32_bf16(a, b, c, 0, 0, 0);
}

__device__ __forceinline__ void barrier_raw() {
  asm volatile("" ::: "memory");
  __builtin_amdgcn_s_barrier();
  asm volatile("" ::: "memory");
}

// ---------------- cast fp32 -> bf16, 4 elems/thread -------------------------
__global__ __launch_bounds__(256) void cast_f32_bf16(const float* __restrict__ in,
                                                     bf16* __restrict__ out, int n4) {
  int i = blockIdx.x * 256 + threadIdx.x;
  if (i >= n4) return;
  f32x4 v = *(const f32x4*)(in + (size_t)i * 4);
  bf16x2 a, b;
  a[0] = (bf16)v[0]; a[1] = (bf16)v[1];
  b[0] = (bf16)v[2]; b[1] = (bf16)v[3];
  *(bf16x2*)(out + (size_t)i * 4)     = a;
  *(bf16x2*)(out + (size_t)i * 4 + 2) = b;
}

// ---------------- transpose+cast: fp32 (R x C) -> bf16 (C x R) --------------
__global__ __launch_bounds__(256) void transpose_cast(const float* __restrict__ in,
                                                      bf16* __restrict__ out, int R, int C) {
  __shared__ float tile[32][33];
  int c0 = blockIdx.x * 32, r0 = blockIdx.y * 32;
  int tx = threadIdx.x, ty = threadIdx.y;
  #pragma unroll
  for (int i = 0; i < 4; ++i)
    tile[ty + i * 8][tx] = in[(size_t)(r0 + ty + i * 8) * C + c0 + tx];
  __syncthreads();
  #pragma unroll
  for (int i = 0; i < 4; ++i)
    out[(size_t)(c0 + ty + i * 8) * R + r0 + tx] = (bf16)tile[tx][ty + i * 8];
}

// ========== 128x128 GEMM (merged K+V projection, outMode 3 splits) ==========
__device__ __forceinline__ void stage128x32(const bf16* __restrict__ A,
                                            const bf16* __restrict__ Bt,
                                            bf16* sA, bf16* sB,
                                            int m0, int n0, int K, int kt, int tid) {
  int wbase = tid & ~63;
  #pragma unroll
  for (int r = 0; r < 2; ++r) {
    int e = (r * 256 + tid) * 8;
    int row = e >> 5, col = e & 31;
    gld16(A  + (size_t)(m0 + row) * K + (size_t)kt * 32 + col,
          sA + (size_t)(r * 256 + wbase) * 8);
    gld16(Bt + (size_t)(n0 + row) * K + (size_t)kt * 32 + col,
          sB + (size_t)(r * 256 + wbase) * 8);
  }
}

// outMode: 0 bf16 row-major; 1 bf16 C^T; 2 fp32 row-major;
//          3 merged KV: col<512 -> Cv row-major (N=512), col>=512 -> Vt^T
__global__ __launch_bounds__(256) void gemm_bt(const bf16* __restrict__ A,
                                               const bf16* __restrict__ Bt,
                                               void* __restrict__ Cv,
                                               bf16* __restrict__ Vtout,
                                               int M, int N, int K, int outMode) {
  __shared__ bf16 sA[2][128 * 32];
  __shared__ bf16 sB[2][128 * 32];
  int nb = N >> 7;
  int bm = (int)blockIdx.x / nb, bn = (int)blockIdx.x % nb;
  int m0 = bm << 7, n0 = bn << 7;
  int tid = threadIdx.x;
  int lane = tid & 63, w = tid >> 6;
  int li = lane & 15, g = lane >> 4, g8 = g * 8;
  int wm = w >> 1, wn = w & 1;
  f32x4 acc[4][4] = {};
  int NT = K >> 5;

  stage128x32(A, Bt, sA[0], sB[0], m0, n0, K, 0, tid);
  __syncthreads();
  for (int kt = 0; kt < NT; ++kt) {
    int cur = kt & 1;
    if (kt + 1 < NT)
      stage128x32(A, Bt, sA[cur ^ 1], sB[cur ^ 1], m0, n0, K, kt + 1, tid);
    bf16x8 af[4], bv[4];
    #pragma unroll
    for (int mt = 0; mt < 4; ++mt)
      af[mt] = *(const bf16x8*)&sA[cur][(wm * 64 + mt * 16 + li) * 32 + g8];
    #pragma unroll
    for (int nt = 0; nt < 4; ++nt)
      bv[nt] = *(const bf16x8*)&sB[cur][(wn * 64 + nt * 16 + li) * 32 + g8];
    #pragma unroll
    for (int mt = 0; mt < 4; ++mt)
      #pragma unroll
      for (int nt = 0; nt < 4; ++nt)
        acc[mt][nt] = mfma16(af[mt], bv[nt], acc[mt][nt]);
    __syncthreads();
  }
  #pragma unroll
  for (int mt = 0; mt < 4; ++mt)
    #pragma unroll
    for (int nt = 0; nt < 4; ++nt)
      #pragma unroll
      for (int j = 0; j < 4; ++j) {
        int row = m0 + wm * 64 + mt * 16 + g * 4 + j;
        int col = n0 + wn * 64 + nt * 16 + li;
        float v = acc[mt][nt][j];
        if (outMode == 0)      ((bf16*)Cv)[(size_t)row * N + col] = (bf16)v;
        else if (outMode == 1) ((bf16*)Cv)[(size_t)col * M + row] = (bf16)v;
        else if (outMode == 2) ((float*)Cv)[(size_t)row * N + col] = v;
        else {  // 3: merged KV
          if (col < 512) ((bf16*)Cv)[(size_t)row * 512 + col] = (bf16)v;
          else           Vtout[(size_t)(col - 512) * M + row] = (bf16)v;
        }
      }
}

// ======= 256x256 8-wave GEMM (round-7 best variant) + fused Q-RoPE ==========
// ONE vmcnt(0)+barrier per K-tile; stages post-barrier spread through tile;
// ds_reads batched with counted lgkmcnt(4). outMode: 0 bf16; 2 fp32;
// 3 bf16 + interleaved RoPE (pair exchange via shfl_xor lane^1).
template<int RSP>  // 64 for A halves, 32 for B halves
__device__ __forceinline__ void stage_quad(const bf16* __restrict__ G,
                                           bf16* __restrict__ sbuf,
                                           int grow0, int K, int k0, int half, int tid) {
  int w = tid >> 6, lane = tid & 63;
  int rl = lane >> 3;                         // row within the 8-row group
  int col = ((lane & 7) ^ rl) * 8;            // inverse-swizzled SOURCE col (rule #21)
  #pragma unroll
  for (int r = 0; r < 2; ++r) {
    int lr0 = r * 64 + w * 8;                 // multiple of 8, 0..120
    int row0 = (lr0 & (RSP - 1)) + half * RSP + (lr0 / RSP) * 2 * RSP;
    gld16(G + (size_t)(grow0 + row0 + rl) * K + k0 + col,
          sbuf + row0 * 64);                  // wave-uniform linear LDS dest
  }
}

__global__ __launch_bounds__(512, 2) void gemm256(const bf16* __restrict__ A,
                                                  const bf16* __restrict__ Bt,
                                                  void* __restrict__ Cv,
                                                  const int* __restrict__ pos,
                                                  int M, int N, int K, int outMode) {
  __shared__ bf16 sA[2][256 * 64];
  __shared__ bf16 sB[2][256 * 64];
  int nb = N >> 8;
  int cpx = (int)gridDim.x >> 3;
  int bid = (int)blockIdx.x;
  int swzb = (bid & 7) * cpx + (bid >> 3);
  int bm = swzb / nb, bn = swzb % nb;
  int m0 = bm << 8, n0 = bn << 8;
  int tid = threadIdx.x, lane = tid & 63, w = tid >> 6;
  int li = lane & 15, g = lane >> 4;
  int wm = w >> 2, wn = w & 3;                // 2 x 4 wave grid
  int swz = (li & 7);

  f32x4 acc[8][4] = {};
  bf16x8 af[4][2];
  bf16x8 bv[2][2][2];

  int NT = K >> 6;

  stage_quad<64>(A,  sA[0], m0, K, 0, 0, tid);
  stage_quad<32>(Bt, sB[0], n0, K, 0, 0, tid);
  stage_quad<32>(Bt, sB[0], n0, K, 0, 1, tid);
  stage_quad<64>(A,  sA[0], m0, K, 0, 1, tid);

#define VMW(n) asm volatile("s_waitcnt vmcnt(" #n ")" ::: "memory")
#define SBAR() __builtin_amdgcn_sched_barrier(0)
#define LGKM(n) { asm volatile("s_waitcnt lgkmcnt(" #n ")" ::: "memory"); \
  __builtin_amdgcn_sched_barrier(0); }
#define LOAD_A256(mh) { _Pragma("unroll") for (int mf = 0; mf < 4; ++mf) \
  _Pragma("unroll") for (int ks = 0; ks < 2; ++ks) { \
    int row = wm * 128 + (mh) * 64 + mf * 16 + li; \
    af[mf][ks] = *(const bf16x8*)&sA[cur][row * 64 + ((ks * 4 + g) ^ swz) * 8]; } }
#define LOAD_B256(nh) { _Pragma("unroll") for (int nf = 0; nf < 2; ++nf) \
  _Pragma("unroll") for (int ks = 0; ks < 2; ++ks) { \
    int row = wn * 64 + (nh) * 32 + nf * 16 + li; \
    bv[nh][nf][ks] = *(const bf16x8*)&sB[cur][row * 64 + ((ks * 4 + g) ^ swz) * 8]; } }
#define MFMA_PH(mh, nh) { \
  __builtin_amdgcn_s_setprio(1); \
  _Pragma("unroll") for (int mf = 0; mf < 4; ++mf) \
  _Pragma("unroll") for (int nf = 0; nf < 2; ++nf) \
  _Pragma("unroll") for (int ks = 0; ks < 2; ++ks) \
    acc[(mh) * 4 + mf][(nh) * 2 + nf] = \
      mfma16(af[mf][ks], bv[nh][nf][ks], acc[(mh) * 4 + mf][(nh) * 2 + nf]); \
  __builtin_amdgcn_s_setprio(0); }

  int cur = 0;
  for (int t = 0; t < NT; ++t) {
    int nxt = cur ^ 1;
    bool pre = (t + 1 < NT);
    int k1 = (t + 1) << 6;
    VMW(0);
    barrier_raw();
    if (pre) stage_quad<64>(A, sA[nxt], m0, K, k1, 0, tid);
    LOAD_A256(0); LOAD_B256(0);
    SBAR();
    LOAD_B256(1);
    if (pre) stage_quad<32>(Bt, sB[nxt], n0, K, k1, 0, tid);
    LGKM(4);
    MFMA_PH(0, 0);
    if (pre) stage_quad<32>(Bt, sB[nxt], n0, K, k1, 1, tid);
    LGKM(0);
    MFMA_PH(0, 1);
    LOAD_A256(1);
    if (pre) stage_quad<64>(A, sA[nxt], m0, K, k1, 1, tid);
    LGKM(0);
    MFMA_PH(1, 1);
    MFMA_PH(1, 0);
    cur = nxt;
  }
#undef VMW
#undef SBAR
#undef LGKM
#undef LOAD_A256
#undef LOAD_B256
#undef MFMA_PH

  if (outMode == 3) {
    // fused interleaved RoPE: pair (2i,2i+1) lives in lanes li, li^1.
    float inv4[4];
    #pragma unroll
    for (int ni = 0; ni < 4; ++ni) {
      int col = n0 + wn * 64 + ni * 16 + li;
      inv4[ni] = __expf((float)((col & 127) >> 1) * -0.14390747054172642f);
    }
    #pragma unroll
    for (int mi = 0; mi < 8; ++mi)
      #pragma unroll
      for (int j = 0; j < 4; ++j) {
        int row = m0 + wm * 128 + mi * 16 + g * 4 + j;
        float pr = (float)pos[row];
        #pragma unroll
        for (int ni = 0; ni < 4; ++ni) {
          int col = n0 + wn * 64 + ni * 16 + li;
          float ang = pr * inv4[ni];
          float s, c;
          sincosf(ang, &s, &c);
          float v = acc[mi][ni][j];
          float pv = __shfl_xor(v, 1);
          float outv = (li & 1) ? (pv * s + v * c) : (v * c - pv * s);
          ((bf16*)Cv)[(size_t)row * N + col] = (bf16)outv;
        }
      }
  } else {
    #pragma unroll
    for (int mi = 0; mi < 8; ++mi)
      #pragma unroll
      for (int ni = 0; ni < 4; ++ni)
        #pragma unroll
        for (int j = 0; j < 4; ++j) {
          int row = m0 + wm * 128 + mi * 16 + g * 4 + j;
          int col = n0 + wn * 64 + ni * 16 + li;
          float v = acc[mi][ni][j];
          if (outMode == 2) ((float*)Cv)[(size_t)row * N + col] = v;
          else              ((bf16*)Cv)[(size_t)row * N + col] = (bf16)v;
        }
  }
}

// ---------------- RoPE in place (used for K only) ---------------------------
__global__ __launch_bounds__(256) void rope_kernel(bf16* __restrict__ X,
                                                   const int* __restrict__ pos,
                                                   int T, int heads) {
  int idx = blockIdx.x * 256 + threadIdx.x;
  int total = T * heads * 64;
  if (idx >= total) return;
  int i = idx & 63;
  int rest = idx >> 6;
  int hh = rest % heads;
  int t = rest / heads;
  float inv = expf((float)i * (-9.210340371976184f / 64.0f));
  float ang = (float)pos[t] * inv;
  float s, c;
  sincosf(ang, &s, &c);
  bf16* p = X + ((size_t)t * heads + hh) * HD + 2 * i;
  bf16x2 xv = *(const bf16x2*)p;
  float xe = (float)xv[0], xo = (float)xv[1];
  bf16x2 r;
  r[0] = (bf16)(xe * c - xo * s);
  r[1] = (bf16)(xe * s + xo * c);
  *(bf16x2*)p = r;
}

// -------- sliding-window GQA flash attention, 4 heads per block -------------
// Block = 64 q-rows x one kv-group (4 q-heads). 8 waves: w = rh*4+hh;
// wave handles 32 rows (2 groups of 16) x head kvh*4+hh. K/V staged ONCE per
// block per tile (4.2x less staging than 1-head blocks). LDS layouts and
// swizzles identical to the verified 1-head kernel.
__global__ __launch_bounds__(512) void attn_kernel(const bf16* __restrict__ Q,
                                                   const bf16* __restrict__ Kb,
                                                   const bf16* __restrict__ Vt,
                                                   const int* __restrict__ pos,
                                                   const int* __restrict__ cu,
                                                   bf16* __restrict__ O, int T, int B) {
  __shared__ bf16 sK[32 * 128];    // chunk stored at chunk^(row&7)
  __shared__ bf16 sVt2[64 * 64];   // row r: d=2r|2r+1, chunk^(r&7)
  __shared__ bf16 sP[8][16 * 40];  // per-wave P tile (one group at a time)
  int bid = blockIdx.x;
  int kvh = bid & (NKV - 1);
  int q0 = (bid >> 2) * 64;
  int tid = threadIdx.x, lane = tid & 63, w = tid >> 6;
  int hh = w & 3, rh = w >> 2;
  int h = kvh * 4 + hh;
  int li = lane & 15, g = lane >> 4, g8 = g * 8;
  int rb0 = q0 + rh * 32;

  int seq_start = 0, seq_end = T;
  for (int b = 0; b < B; ++b) {
    int a = cu[b], e = cu[b + 1];
    if (q0 >= a && q0 < e) { seq_start = a; seq_end = e; }
  }

  bf16x8 qf[2][4];
  #pragma unroll
  for (int grp = 0; grp < 2; ++grp)
    #pragma unroll
    for (int kd = 0; kd < 4; ++kd)
      qf[grp][kd] = *(const bf16x8*)(Q + (size_t)(rb0 + grp * 16 + li) * HIDDEN
                                     + h * HD + kd * 32 + g8);

  int pq[2][4], pmin[2], pmax[2];
  #pragma unroll
  for (int grp = 0; grp < 2; ++grp) {
    #pragma unroll
    for (int j = 0; j < 4; ++j) pq[grp][j] = pos[rb0 + grp * 16 + g * 4 + j];
    pmin[grp] = pos[rb0 + grp * 16];
    pmax[grp] = pos[rb0 + grp * 16 + 15];
  }

  float lsum[2][4] = {};
  f32x4 acc[2][8] = {};
  int kstart = q0 - WINDOW;
  if (kstart < seq_start) kstart = seq_start;
  int kend = q0 + 64;
  if (kend > seq_end) kend = seq_end;
  const float scale = 0.08838834764831845f;

  for (int kb = kstart; kb < kend; kb += 32) {
    int wbase = (tid & ~63) * 8;             // element offset of wave's chunk run
    {
      int n = tid;                           // 512 threads cover 512 chunks each
      int krow = n >> 4, kc = (n & 15) ^ (krow & 7);
      gld16(Kb + (size_t)(kb + krow) * (NKV * HD) + kvh * HD + kc * 8, sK + wbase);
      int vr = n >> 3, vc = (n & 7) ^ (vr & 7);
      int vd = 2 * vr + (vc >> 2), vkey = (vc & 3) * 8;
      gld16(Vt + (size_t)(kvh * HD + vd) * T + kb + vkey, sVt2 + wbase);
    }
    __syncthreads();

    int pkf = pos[kb], pkl = pos[kb + 31];
    int pk0 = pos[kb + li], pk1 = pos[kb + 16 + li];
    #pragma unroll
    for (int grp = 0; grp < 2; ++grp) {
      if (pkf > pmax[grp] || pkl < pmin[grp] - WINDOW) continue;  // wave-uniform
      f32x4 s0v = {0.f, 0.f, 0.f, 0.f}, s1v = {0.f, 0.f, 0.f, 0.f};
      #pragma unroll
      for (int kd = 0; kd < 4; ++kd) {
        int c0 = (kd * 4 + g) ^ (li & 7);
        bf16x8 b0 = *(const bf16x8*)&sK[li * 128 + c0 * 8];
        bf16x8 b1 = *(const bf16x8*)&sK[(16 + li) * 128 + c0 * 8];
        s0v = mfma16(qf[grp][kd], b0, s0v);
        s1v = mfma16(qf[grp][kd], b1, s1v);
      }
      bool interior = (pkl <= pmin[grp]) && (pmax[grp] - pkf <= WINDOW);
      if (interior) {
        #pragma unroll
        for (int j = 0; j < 4; ++j) {
          float p0 = __expf(s0v[j] * scale);
          float p1 = __expf(s1v[j] * scale);
          lsum[grp][j] += p0 + p1;
          sP[w][(g * 4 + j) * 40 + li]      = (bf16)p0;
          sP[w][(g * 4 + j) * 40 + 16 + li] = (bf16)p1;
        }
      } else {
        #pragma unroll
        for (int j = 0; j < 4; ++j) {
          int d0 = pq[grp][j] - pk0, d1 = pq[grp][j] - pk1;
          float p0 = (d0 >= 0 && d0 <= WINDOW) ? __expf(s0v[j] * scale) : 0.f;
          float p1 = (d1 >= 0 && d1 <= WINDOW) ? __expf(s1v[j] * scale) : 0.f;
          lsum[grp][j] += p0 + p1;
          sP[w][(g * 4 + j) * 40 + li]      = (bf16)p0;
          sP[w][(g * 4 + j) * 40 + 16 + li] = (bf16)p1;
        }
      }
      bf16x8 pa = *(const bf16x8*)&sP[w][li * 40 + g8];
      #pragma unroll
      for (int dt = 0; dt < 8; ++dt) {
        int d = dt * 16 + li;
        int vr2 = d >> 1;
        int vc2 = ((d & 1) * 4 + g) ^ (vr2 & 7);
        bf16x8 vf = *(const bf16x8*)&sVt2[vr2 * 64 + vc2 * 8];
        acc[grp][dt] = mfma16(pa, vf, acc[grp][dt]);
      }
    }
    __syncthreads();
  }

  #pragma unroll
  for (int grp = 0; grp < 2; ++grp)
    #pragma unroll
    for (int j = 0; j < 4; ++j) {
      float rs = lsum[grp][j];
      rs += __shfl_xor(rs, 1);
      rs += __shfl_xor(rs, 2);
      rs += __shfl_xor(rs, 4);
      rs += __shfl_xor(rs, 8);
      float invl = 1.0f / rs;
      size_t base = (size_t)(rb0 + grp * 16 + g * 4 + j) * HIDDEN + h * HD;
      #pragma unroll
      for (int dt = 0; dt < 8; ++dt)
        O[base + dt * 16 + li] = (bf16)(acc[grp][dt][j] * invl);
    }
}

// ---------------- launcher --------------------------------------------------
extern "C" void kernel_launch(void* const* d_in, const int* in_sizes, int n_in,
                              void* d_out, int out_size, void* d_ws, size_t ws_size,
                              hipStream_t stream) {
  const float* X  = (const float*)d_in[0];
  const float* qw = (const float*)d_in[1];
  const float* kw = (const float*)d_in[2];
  const float* vw = (const float*)d_in[3];
  const float* ow = (const float*)d_in[4];
  const int* pos = (const int*)d_in[5];
  const int* cu  = (const int*)d_in[6];
  int T = in_sizes[0] / HIDDEN;     // 8192
  int B = in_sizes[6] - 1;          // 4
  float* out = (float*)d_out;

  bf16* ws = (bf16*)d_ws;
  size_t off = 0;
  bf16* Xb    = ws + off; off += (size_t)T * HIDDEN;
  bf16* Qb    = ws + off; off += (size_t)T * HIDDEN;       // Q (roped), then attn out
  bf16* Kb    = ws + off; off += (size_t)T * (NKV * HD);
  bf16* Vt    = ws + off; off += (size_t)T * (NKV * HD);
  bf16* qwT   = ws + off; off += (size_t)HIDDEN * HIDDEN;
  bf16* kvwT  = ws + off; off += (size_t)1024 * HIDDEN;    // [kwT; vwT] stacked
  bf16* owT   = ws + off; off += (size_t)HIDDEN * HIDDEN;

  cast_f32_bf16<<<(T * HIDDEN / 4 + 255) / 256, 256, 0, stream>>>(X, Xb, T * HIDDEN / 4);

  dim3 tb(32, 8);
  transpose_cast<<<dim3(HIDDEN / 32, HIDDEN / 32), tb, 0, stream>>>(qw, qwT, HIDDEN, HIDDEN);
  transpose_cast<<<dim3(512 / 32, HIDDEN / 32), tb, 0, stream>>>(kw, kvwT, HIDDEN, 512);
  transpose_cast<<<dim3(512 / 32, HIDDEN / 32), tb, 0, stream>>>(vw, kvwT + (size_t)512 * HIDDEN, HIDDEN, 512);
  transpose_cast<<<dim3(HIDDEN / 32, HIDDEN / 32), tb, 0, stream>>>(ow, owT, HIDDEN, HIDDEN);

  // Q-projection with fused RoPE (outMode 3), grid 256
  gemm256<<<(T / 256) * (HIDDEN / 256), 512, 0, stream>>>(Xb, qwT, Qb, pos, T, HIDDEN, HIDDEN, 3);
  // merged K+V projection: 512 blocks, split epilogue (K row-major, V^T)
  gemm_bt<<<(T / 128) * (1024 / 128), 256, 0, stream>>>(Xb, kvwT, Kb, Vt, T, 1024, HIDDEN, 3);

  // RoPE on K only (Q already roped in-epilogue)
  rope_kernel<<<(T * NKV * 64 + 255) / 256, 256, 0, stream>>>(Kb, pos, T, NKV);

  // attention: 4 heads per block, grid (T/64)*NKV = 512
  attn_kernel<<<(T / 64) * NKV, 512, 0, stream>>>(Qb, Kb, Vt, pos, cu, Qb, T, B);

  // O-projection (fp32 out), grid 256
  gemm256<<<(T / 256) * (HIDDEN / 256), 512, 0, stream>>>(Qb, owT, out, nullptr, T, HIDDEN, HIDDEN, 2);
}

// Round 11
// 347.892 us; speedup vs baseline: 1.2467x; 1.1672x over previous
//
#include <hip/hip_runtime.h>
#include <hip/hip_bf16.h>
#include <cstdint>
#include <cstddef>

typedef __bf16 bf16;
typedef __bf16 bf16x2 __attribute__((ext_vector_type(2)));
typedef __bf16 bf16x8 __attribute__((ext_vector_type(8)));
typedef float  f32x4  __attribute__((ext_vector_type(4)));

#define HIDDEN 2048
#define NHEADS 16
#define NKV    4
#define HD     128
#define WINDOW 512

// async global->LDS, 16B per lane; LDS dest is wave-uniform base + lane*16
__device__ __forceinline__ void gld16(const void* g, void* s) {
  __builtin_amdgcn_global_load_lds((const __attribute__((address_space(1))) void*)g,
                                   (__attribute__((address_space(3))) void*)s, 16, 0, 0);
}

__device__ __forceinline__ f32x4 mfma16(bf16x8 a, bf16x8 b, f32x4 c) {
  return __builtin_amdgcn_mfma_f32_16x16x32_bf16(a, b, c, 0, 0, 0);
}

__device__ __forceinline__ void barrier_raw() {
  asm volatile("" ::: "memory");
  __builtin_amdgcn_s_barrier();
  asm volatile("" ::: "memory");
}

// ---------------- cast fp32 -> bf16, 4 elems/thread -------------------------
__global__ __launch_bounds__(256) void cast_f32_bf16(const float* __restrict__ in,
                                                     bf16* __restrict__ out, int n4) {
  int i = blockIdx.x * 256 + threadIdx.x;
  if (i >= n4) return;
  f32x4 v = *(const f32x4*)(in + (size_t)i * 4);
  bf16x2 a, b;
  a[0] = (bf16)v[0]; a[1] = (bf16)v[1];
  b[0] = (bf16)v[2]; b[1] = (bf16)v[3];
  *(bf16x2*)(out + (size_t)i * 4)     = a;
  *(bf16x2*)(out + (size_t)i * 4 + 2) = b;
}

// ---------------- transpose+cast: fp32 (R x C) -> bf16 (C x R) --------------
__global__ __launch_bounds__(256) void transpose_cast(const float* __restrict__ in,
                                                      bf16* __restrict__ out, int R, int C) {
  __shared__ float tile[32][33];
  int c0 = blockIdx.x * 32, r0 = blockIdx.y * 32;
  int tx = threadIdx.x, ty = threadIdx.y;
  #pragma unroll
  for (int i = 0; i < 4; ++i)
    tile[ty + i * 8][tx] = in[(size_t)(r0 + ty + i * 8) * C + c0 + tx];
  __syncthreads();
  #pragma unroll
  for (int i = 0; i < 4; ++i)
    out[(size_t)(c0 + ty + i * 8) * R + r0 + tx] = (bf16)tile[tx][ty + i * 8];
}

// ========== 128x128 GEMM (merged K+V projection, outMode 3 splits) ==========
__device__ __forceinline__ void stage128x32(const bf16* __restrict__ A,
                                            const bf16* __restrict__ Bt,
                                            bf16* sA, bf16* sB,
                                            int m0, int n0, int K, int kt, int tid) {
  int wbase = tid & ~63;
  #pragma unroll
  for (int r = 0; r < 2; ++r) {
    int e = (r * 256 + tid) * 8;
    int row = e >> 5, col = e & 31;
    gld16(A  + (size_t)(m0 + row) * K + (size_t)kt * 32 + col,
          sA + (size_t)(r * 256 + wbase) * 8);
    gld16(Bt + (size_t)(n0 + row) * K + (size_t)kt * 32 + col,
          sB + (size_t)(r * 256 + wbase) * 8);
  }
}

// outMode: 0 bf16 row-major; 1 bf16 C^T; 2 fp32 row-major;
//          3 merged KV: col<512 -> Cv row-major (N=512), col>=512 -> Vt^T
__global__ __launch_bounds__(256) void gemm_bt(const bf16* __restrict__ A,
                                               const bf16* __restrict__ Bt,
                                               void* __restrict__ Cv,
                                               bf16* __restrict__ Vtout,
                                               int M, int N, int K, int outMode) {
  __shared__ bf16 sA[2][128 * 32];
  __shared__ bf16 sB[2][128 * 32];
  int nb = N >> 7;
  int bm = (int)blockIdx.x / nb, bn = (int)blockIdx.x % nb;
  int m0 = bm << 7, n0 = bn << 7;
  int tid = threadIdx.x;
  int lane = tid & 63, w = tid >> 6;
  int li = lane & 15, g = lane >> 4, g8 = g * 8;
  int wm = w >> 1, wn = w & 1;
  f32x4 acc[4][4] = {};
  int NT = K >> 5;

  stage128x32(A, Bt, sA[0], sB[0], m0, n0, K, 0, tid);
  __syncthreads();
  for (int kt = 0; kt < NT; ++kt) {
    int cur = kt & 1;
    if (kt + 1 < NT)
      stage128x32(A, Bt, sA[cur ^ 1], sB[cur ^ 1], m0, n0, K, kt + 1, tid);
    bf16x8 af[4], bv[4];
    #pragma unroll
    for (int mt = 0; mt < 4; ++mt)
      af[mt] = *(const bf16x8*)&sA[cur][(wm * 64 + mt * 16 + li) * 32 + g8];
    #pragma unroll
    for (int nt = 0; nt < 4; ++nt)
      bv[nt] = *(const bf16x8*)&sB[cur][(wn * 64 + nt * 16 + li) * 32 + g8];
    #pragma unroll
    for (int mt = 0; mt < 4; ++mt)
      #pragma unroll
      for (int nt = 0; nt < 4; ++nt)
        acc[mt][nt] = mfma16(af[mt], bv[nt], acc[mt][nt]);
    __syncthreads();
  }
  #pragma unroll
  for (int mt = 0; mt < 4; ++mt)
    #pragma unroll
    for (int nt = 0; nt < 4; ++nt)
      #pragma unroll
      for (int j = 0; j < 4; ++j) {
        int row = m0 + wm * 64 + mt * 16 + g * 4 + j;
        int col = n0 + wn * 64 + nt * 16 + li;
        float v = acc[mt][nt][j];
        if (outMode == 0)      ((bf16*)Cv)[(size_t)row * N + col] = (bf16)v;
        else if (outMode == 1) ((bf16*)Cv)[(size_t)col * M + row] = (bf16)v;
        else if (outMode == 2) ((float*)Cv)[(size_t)row * N + col] = v;
        else {  // 3: merged KV
          if (col < 512) ((bf16*)Cv)[(size_t)row * 512 + col] = (bf16)v;
          else           Vtout[(size_t)(col - 512) * M + row] = (bf16)v;
        }
      }
}

// ============== 256x256 8-wave GEMM (round-7 best variant) ==================
// ONE vmcnt(0)+barrier per K-tile; stages post-barrier spread through tile;
// ds_reads batched with counted lgkmcnt(4). outMode: 0 bf16; 2 fp32.
template<int RSP>  // 64 for A halves, 32 for B halves
__device__ __forceinline__ void stage_quad(const bf16* __restrict__ G,
                                           bf16* __restrict__ sbuf,
                                           int grow0, int K, int k0, int half, int tid) {
  int w = tid >> 6, lane = tid & 63;
  int rl = lane >> 3;                         // row within the 8-row group
  int col = ((lane & 7) ^ rl) * 8;            // inverse-swizzled SOURCE col (rule #21)
  #pragma unroll
  for (int r = 0; r < 2; ++r) {
    int lr0 = r * 64 + w * 8;                 // multiple of 8, 0..120
    int row0 = (lr0 & (RSP - 1)) + half * RSP + (lr0 / RSP) * 2 * RSP;
    gld16(G + (size_t)(grow0 + row0 + rl) * K + k0 + col,
          sbuf + row0 * 64);                  // wave-uniform linear LDS dest
  }
}

__global__ __launch_bounds__(512, 2) void gemm256(const bf16* __restrict__ A,
                                                  const bf16* __restrict__ Bt,
                                                  void* __restrict__ Cv,
                                                  int M, int N, int K, int outMode) {
  __shared__ bf16 sA[2][256 * 64];
  __shared__ bf16 sB[2][256 * 64];
  int nb = N >> 8;
  int cpx = (int)gridDim.x >> 3;
  int bid = (int)blockIdx.x;
  int swzb = (bid & 7) * cpx + (bid >> 3);
  int bm = swzb / nb, bn = swzb % nb;
  int m0 = bm << 8, n0 = bn << 8;
  int tid = threadIdx.x, lane = tid & 63, w = tid >> 6;
  int li = lane & 15, g = lane >> 4;
  int wm = w >> 2, wn = w & 3;                // 2 x 4 wave grid
  int swz = (li & 7);

  f32x4 acc[8][4] = {};
  bf16x8 af[4][2];
  bf16x8 bv[2][2][2];

  int NT = K >> 6;

  stage_quad<64>(A,  sA[0], m0, K, 0, 0, tid);
  stage_quad<32>(Bt, sB[0], n0, K, 0, 0, tid);
  stage_quad<32>(Bt, sB[0], n0, K, 0, 1, tid);
  stage_quad<64>(A,  sA[0], m0, K, 0, 1, tid);

#define VMW(n) asm volatile("s_waitcnt vmcnt(" #n ")" ::: "memory")
#define SBAR() __builtin_amdgcn_sched_barrier(0)
#define LGKM(n) { asm volatile("s_waitcnt lgkmcnt(" #n ")" ::: "memory"); \
  __builtin_amdgcn_sched_barrier(0); }
#define LOAD_A256(mh) { _Pragma("unroll") for (int mf = 0; mf < 4; ++mf) \
  _Pragma("unroll") for (int ks = 0; ks < 2; ++ks) { \
    int row = wm * 128 + (mh) * 64 + mf * 16 + li; \
    af[mf][ks] = *(const bf16x8*)&sA[cur][row * 64 + ((ks * 4 + g) ^ swz) * 8]; } }
#define LOAD_B256(nh) { _Pragma("unroll") for (int nf = 0; nf < 2; ++nf) \
  _Pragma("unroll") for (int ks = 0; ks < 2; ++ks) { \
    int row = wn * 64 + (nh) * 32 + nf * 16 + li; \
    bv[nh][nf][ks] = *(const bf16x8*)&sB[cur][row * 64 + ((ks * 4 + g) ^ swz) * 8]; } }
#define MFMA_PH(mh, nh) { \
  __builtin_amdgcn_s_setprio(1); \
  _Pragma("unroll") for (int mf = 0; mf < 4; ++mf) \
  _Pragma("unroll") for (int nf = 0; nf < 2; ++nf) \
  _Pragma("unroll") for (int ks = 0; ks < 2; ++ks) \
    acc[(mh) * 4 + mf][(nh) * 2 + nf] = \
      mfma16(af[mf][ks], bv[nh][nf][ks], acc[(mh) * 4 + mf][(nh) * 2 + nf]); \
  __builtin_amdgcn_s_setprio(0); }

  int cur = 0;
  for (int t = 0; t < NT; ++t) {
    int nxt = cur ^ 1;
    bool pre = (t + 1 < NT);
    int k1 = (t + 1) << 6;
    VMW(0);
    barrier_raw();
    if (pre) stage_quad<64>(A, sA[nxt], m0, K, k1, 0, tid);
    LOAD_A256(0); LOAD_B256(0);
    SBAR();
    LOAD_B256(1);
    if (pre) stage_quad<32>(Bt, sB[nxt], n0, K, k1, 0, tid);
    LGKM(4);
    MFMA_PH(0, 0);
    if (pre) stage_quad<32>(Bt, sB[nxt], n0, K, k1, 1, tid);
    LGKM(0);
    MFMA_PH(0, 1);
    LOAD_A256(1);
    if (pre) stage_quad<64>(A, sA[nxt], m0, K, k1, 1, tid);
    LGKM(0);
    MFMA_PH(1, 1);
    MFMA_PH(1, 0);
    cur = nxt;
  }
#undef VMW
#undef SBAR
#undef LGKM
#undef LOAD_A256
#undef LOAD_B256
#undef MFMA_PH

  #pragma unroll
  for (int mi = 0; mi < 8; ++mi)
    #pragma unroll
    for (int ni = 0; ni < 4; ++ni)
      #pragma unroll
      for (int j = 0; j < 4; ++j) {
        int row = m0 + wm * 128 + mi * 16 + g * 4 + j;
        int col = n0 + wn * 64 + ni * 16 + li;
        float v = acc[mi][ni][j];
        if (outMode == 2) ((float*)Cv)[(size_t)row * N + col] = v;
        else              ((bf16*)Cv)[(size_t)row * N + col] = (bf16)v;
      }
}

// ---------------- RoPE in place: X (T x heads*128), interleaved pairs -------
__global__ __launch_bounds__(256) void rope_kernel(bf16* __restrict__ X,
                                                   const int* __restrict__ pos,
                                                   int T, int heads) {
  int idx = blockIdx.x * 256 + threadIdx.x;
  int total = T * heads * 64;
  if (idx >= total) return;
  int i = idx & 63;
  int rest = idx >> 6;
  int hh = rest % heads;
  int t = rest / heads;
  float inv = expf((float)i * (-9.210340371976184f / 64.0f));
  float ang = (float)pos[t] * inv;
  float s, c;
  sincosf(ang, &s, &c);
  bf16* p = X + ((size_t)t * heads + hh) * HD + 2 * i;
  bf16x2 xv = *(const bf16x2*)p;
  float xe = (float)xv[0], xo = (float)xv[1];
  bf16x2 r;
  r[0] = (bf16)(xe * c - xo * s);
  r[1] = (bf16)(xe * s + xo * c);
  *(bf16x2*)p = r;
}

// -------- sliding-window GQA flash attention, 4 heads per block -------------
// Block = 64 q-rows x one kv-group (4 q-heads). 8 waves: w = rh*4+hh;
// wave handles 32 rows (2 groups of 16) x head kvh*4+hh. K/V staged ONCE per
// block per tile (4x less staging than 1-head blocks).
__global__ __launch_bounds__(512) void attn_kernel(const bf16* __restrict__ Q,
                                                   const bf16* __restrict__ Kb,
                                                   const bf16* __restrict__ Vt,
                                                   const int* __restrict__ pos,
                                                   const int* __restrict__ cu,
                                                   bf16* __restrict__ O, int T, int B) {
  __shared__ bf16 sK[32 * 128];    // chunk stored at chunk^(row&7)
  __shared__ bf16 sVt2[64 * 64];   // row r: d=2r|2r+1, chunk^(r&7)
  __shared__ bf16 sP[8][16 * 40];  // per-wave P tile (one group at a time)
  int bid = blockIdx.x;
  int kvh = bid & (NKV - 1);
  int q0 = (bid >> 2) * 64;
  int tid = threadIdx.x, lane = tid & 63, w = tid >> 6;
  int hh = w & 3, rh = w >> 2;
  int h = kvh * 4 + hh;
  int li = lane & 15, g = lane >> 4, g8 = g * 8;
  int rb0 = q0 + rh * 32;

  int seq_start = 0, seq_end = T;
  for (int b = 0; b < B; ++b) {
    int a = cu[b], e = cu[b + 1];
    if (q0 >= a && q0 < e) { seq_start = a; seq_end = e; }
  }

  bf16x8 qf[2][4];
  #pragma unroll
  for (int grp = 0; grp < 2; ++grp)
    #pragma unroll
    for (int kd = 0; kd < 4; ++kd)
      qf[grp][kd] = *(const bf16x8*)(Q + (size_t)(rb0 + grp * 16 + li) * HIDDEN
                                     + h * HD + kd * 32 + g8);

  int pq[2][4], pmin[2], pmax[2];
  #pragma unroll
  for (int grp = 0; grp < 2; ++grp) {
    #pragma unroll
    for (int j = 0; j < 4; ++j) pq[grp][j] = pos[rb0 + grp * 16 + g * 4 + j];
    pmin[grp] = pos[rb0 + grp * 16];
    pmax[grp] = pos[rb0 + grp * 16 + 15];
  }

  float lsum[2][4] = {};
  f32x4 acc[2][8] = {};
  int kstart = q0 - WINDOW;
  if (kstart < seq_start) kstart = seq_start;
  int kend = q0 + 64;
  if (kend > seq_end) kend = seq_end;
  const float scale = 0.08838834764831845f;

  for (int kb = kstart; kb < kend; kb += 32) {
    int wbase = (tid & ~63) * 8;             // element offset of wave's chunk run
    {
      int n = tid;                           // 512 threads cover 512 chunks each
      int krow = n >> 4, kc = (n & 15) ^ (krow & 7);
      gld16(Kb + (size_t)(kb + krow) * (NKV * HD) + kvh * HD + kc * 8, sK + wbase);
      int vr = n >> 3, vc = (n & 7) ^ (vr & 7);
      int vd = 2 * vr + (vc >> 2), vkey = (vc & 3) * 8;
      gld16(Vt + (size_t)(kvh * HD + vd) * T + kb + vkey, sVt2 + wbase);
    }
    __syncthreads();

    int pkf = pos[kb], pkl = pos[kb + 31];
    int pk0 = pos[kb + li], pk1 = pos[kb + 16 + li];
    #pragma unroll
    for (int grp = 0; grp < 2; ++grp) {
      if (pkf > pmax[grp] || pkl < pmin[grp] - WINDOW) continue;  // wave-uniform
      f32x4 s0v = {0.f, 0.f, 0.f, 0.f}, s1v = {0.f, 0.f, 0.f, 0.f};
      #pragma unroll
      for (int kd = 0; kd < 4; ++kd) {
        int c0 = (kd * 4 + g) ^ (li & 7);
        bf16x8 b0 = *(const bf16x8*)&sK[li * 128 + c0 * 8];
        bf16x8 b1 = *(const bf16x8*)&sK[(16 + li) * 128 + c0 * 8];
        s0v = mfma16(qf[grp][kd], b0, s0v);
        s1v = mfma16(qf[grp][kd], b1, s1v);
      }
      bool interior = (pkl <= pmin[grp]) && (pmax[grp] - pkf <= WINDOW);
      if (interior) {
        #pragma unroll
        for (int j = 0; j < 4; ++j) {
          float p0 = __expf(s0v[j] * scale);
          float p1 = __expf(s1v[j] * scale);
          lsum[grp][j] += p0 + p1;
          sP[w][(g * 4 + j) * 40 + li]      = (bf16)p0;
          sP[w][(g * 4 + j) * 40 + 16 + li] = (bf16)p1;
        }
      } else {
        #pragma unroll
        for (int j = 0; j < 4; ++j) {
          int d0 = pq[grp][j] - pk0, d1 = pq[grp][j] - pk1;
          float p0 = (d0 >= 0 && d0 <= WINDOW) ? __expf(s0v[j] * scale) : 0.f;
          float p1 = (d1 >= 0 && d1 <= WINDOW) ? __expf(s1v[j] * scale) : 0.f;
          lsum[grp][j] += p0 + p1;
          sP[w][(g * 4 + j) * 40 + li]      = (bf16)p0;
          sP[w][(g * 4 + j) * 40 + 16 + li] = (bf16)p1;
        }
      }
      bf16x8 pa = *(const bf16x8*)&sP[w][li * 40 + g8];
      #pragma unroll
      for (int dt = 0; dt < 8; ++dt) {
        int d = dt * 16 + li;
        int vr2 = d >> 1;
        int vc2 = ((d & 1) * 4 + g) ^ (vr2 & 7);
        bf16x8 vf = *(const bf16x8*)&sVt2[vr2 * 64 + vc2 * 8];
        acc[grp][dt] = mfma16(pa, vf, acc[grp][dt]);
      }
    }
    __syncthreads();
  }

  #pragma unroll
  for (int grp = 0; grp < 2; ++grp)
    #pragma unroll
    for (int j = 0; j < 4; ++j) {
      float rs = lsum[grp][j];
      rs += __shfl_xor(rs, 1);
      rs += __shfl_xor(rs, 2);
      rs += __shfl_xor(rs, 4);
      rs += __shfl_xor(rs, 8);
      float invl = 1.0f / rs;
      size_t base = (size_t)(rb0 + grp * 16 + g * 4 + j) * HIDDEN + h * HD;
      #pragma unroll
      for (int dt = 0; dt < 8; ++dt)
        O[base + dt * 16 + li] = (bf16)(acc[grp][dt][j] * invl);
    }
}

// ---------------- launcher --------------------------------------------------
extern "C" void kernel_launch(void* const* d_in, const int* in_sizes, int n_in,
                              void* d_out, int out_size, void* d_ws, size_t ws_size,
                              hipStream_t stream) {
  const float* X  = (const float*)d_in[0];
  const float* qw = (const float*)d_in[1];
  const float* kw = (const float*)d_in[2];
  const float* vw = (const float*)d_in[3];
  const float* ow = (const float*)d_in[4];
  const int* pos = (const int*)d_in[5];
  const int* cu  = (const int*)d_in[6];
  int T = in_sizes[0] / HIDDEN;     // 8192
  int B = in_sizes[6] - 1;          // 4
  float* out = (float*)d_out;

  bf16* ws = (bf16*)d_ws;
  size_t off = 0;
  bf16* Xb    = ws + off; off += (size_t)T * HIDDEN;
  bf16* Qb    = ws + off; off += (size_t)T * HIDDEN;       // Q, then attn out
  bf16* Kb    = ws + off; off += (size_t)T * (NKV * HD);
  bf16* Vt    = ws + off; off += (size_t)T * (NKV * HD);
  bf16* qwT   = ws + off; off += (size_t)HIDDEN * HIDDEN;
  bf16* kvwT  = ws + off; off += (size_t)1024 * HIDDEN;    // [kwT; vwT] stacked
  bf16* owT   = ws + off; off += (size_t)HIDDEN * HIDDEN;

  cast_f32_bf16<<<(T * HIDDEN / 4 + 255) / 256, 256, 0, stream>>>(X, Xb, T * HIDDEN / 4);

  dim3 tb(32, 8);
  transpose_cast<<<dim3(HIDDEN / 32, HIDDEN / 32), tb, 0, stream>>>(qw, qwT, HIDDEN, HIDDEN);
  transpose_cast<<<dim3(512 / 32, HIDDEN / 32), tb, 0, stream>>>(kw, kvwT, HIDDEN, 512);
  transpose_cast<<<dim3(512 / 32, HIDDEN / 32), tb, 0, stream>>>(vw, kvwT + (size_t)512 * HIDDEN, HIDDEN, 512);
  transpose_cast<<<dim3(HIDDEN / 32, HIDDEN / 32), tb, 0, stream>>>(ow, owT, HIDDEN, HIDDEN);

  // Q-projection (bf16 out), grid 256
  gemm256<<<(T / 256) * (HIDDEN / 256), 512, 0, stream>>>(Xb, qwT, Qb, T, HIDDEN, HIDDEN, 0);
  // merged K+V projection: 512 blocks, split epilogue (K row-major, V^T)
  gemm_bt<<<(T / 128) * (1024 / 128), 256, 0, stream>>>(Xb, kvwT, Kb, Vt, T, 1024, HIDDEN, 3);

  // RoPE (separate kernels: precise sincosf, no scratch in GEMM epilogue)
  rope_kernel<<<(T * NHEADS * 64 + 255) / 256, 256, 0, stream>>>(Qb, pos, T, NHEADS);
  rope_kernel<<<(T * NKV * 64 + 255) / 256, 256, 0, stream>>>(Kb, pos, T, NKV);

  // attention: 4 heads per block, grid (T/64)*NKV = 512
  attn_kernel<<<(T / 64) * NKV, 512, 0, stream>>>(Qb, Kb, Vt, pos, cu, Qb, T, B);

  // O-projection (fp32 out), grid 256
  gemm256<<<(T / 256) * (HIDDEN / 256), 512, 0, stream>>>(Qb, owT, out, T, HIDDEN, HIDDEN, 2);
}

// Round 12
// 335.667 us; speedup vs baseline: 1.2921x; 1.0364x over previous
//
#include <hip/hip_runtime.h>
#include <hip/hip_bf16.h>
#include <cstdint>
#include <cstddef>

typedef __bf16 bf16;
typedef __bf16 bf16x2 __attribute__((ext_vector_type(2)));
typedef __bf16 bf16x8 __attribute__((ext_vector_type(8)));
typedef float  f32x4  __attribute__((ext_vector_type(4)));

#define HIDDEN 2048
#define NHEADS 16
#define NKV    4
#define HD     128
#define WINDOW 512

// async global->LDS, 16B per lane; LDS dest is wave-uniform base + lane*16
__device__ __forceinline__ void gld16(const void* g, void* s) {
  __builtin_amdgcn_global_load_lds((const __attribute__((address_space(1))) void*)g,
                                   (__attribute__((address_space(3))) void*)s, 16, 0, 0);
}

__device__ __forceinline__ f32x4 mfma16(bf16x8 a, bf16x8 b, f32x4 c) {
  return __builtin_amdgcn_mfma_f32_16x16x32_bf16(a, b, c, 0, 0, 0);
}

__device__ __forceinline__ void barrier_raw() {
  asm volatile("" ::: "memory");
  __builtin_amdgcn_s_barrier();
  asm volatile("" ::: "memory");
}

// ---------------- cast fp32 -> bf16, 4 elems/thread -------------------------
__global__ __launch_bounds__(256) void cast_f32_bf16(const float* __restrict__ in,
                                                     bf16* __restrict__ out, int n4) {
  int i = blockIdx.x * 256 + threadIdx.x;
  if (i >= n4) return;
  f32x4 v = *(const f32x4*)(in + (size_t)i * 4);
  bf16x2 a, b;
  a[0] = (bf16)v[0]; a[1] = (bf16)v[1];
  b[0] = (bf16)v[2]; b[1] = (bf16)v[3];
  *(bf16x2*)(out + (size_t)i * 4)     = a;
  *(bf16x2*)(out + (size_t)i * 4 + 2) = b;
}

// ---------------- transpose+cast: fp32 (R x C) -> bf16 (C x R) --------------
__global__ __launch_bounds__(256) void transpose_cast(const float* __restrict__ in,
                                                      bf16* __restrict__ out, int R, int C) {
  __shared__ float tile[32][33];
  int c0 = blockIdx.x * 32, r0 = blockIdx.y * 32;
  int tx = threadIdx.x, ty = threadIdx.y;
  #pragma unroll
  for (int i = 0; i < 4; ++i)
    tile[ty + i * 8][tx] = in[(size_t)(r0 + ty + i * 8) * C + c0 + tx];
  __syncthreads();
  #pragma unroll
  for (int i = 0; i < 4; ++i)
    out[(size_t)(c0 + ty + i * 8) * R + r0 + tx] = (bf16)tile[tx][ty + i * 8];
}

// ========== 128x128 GEMM (merged K+V projection, outMode 3 splits) ==========
__device__ __forceinline__ void stage128x32(const bf16* __restrict__ A,
                                            const bf16* __restrict__ Bt,
                                            bf16* sA, bf16* sB,
                                            int m0, int n0, int K, int kt, int tid) {
  int wbase = tid & ~63;
  #pragma unroll
  for (int r = 0; r < 2; ++r) {
    int e = (r * 256 + tid) * 8;
    int row = e >> 5, col = e & 31;
    gld16(A  + (size_t)(m0 + row) * K + (size_t)kt * 32 + col,
          sA + (size_t)(r * 256 + wbase) * 8);
    gld16(Bt + (size_t)(n0 + row) * K + (size_t)kt * 32 + col,
          sB + (size_t)(r * 256 + wbase) * 8);
  }
}

// outMode: 0 bf16 row-major; 1 bf16 C^T; 2 fp32 row-major;
//          3 merged KV: col<512 -> Cv row-major (N=512), col>=512 -> Vt^T
__global__ __launch_bounds__(256) void gemm_bt(const bf16* __restrict__ A,
                                               const bf16* __restrict__ Bt,
                                               void* __restrict__ Cv,
                                               bf16* __restrict__ Vtout,
                                               int M, int N, int K, int outMode) {
  __shared__ bf16 sA[2][128 * 32];
  __shared__ bf16 sB[2][128 * 32];
  int nb = N >> 7;
  int bm = (int)blockIdx.x / nb, bn = (int)blockIdx.x % nb;
  int m0 = bm << 7, n0 = bn << 7;
  int tid = threadIdx.x;
  int lane = tid & 63, w = tid >> 6;
  int li = lane & 15, g = lane >> 4, g8 = g * 8;
  int wm = w >> 1, wn = w & 1;
  f32x4 acc[4][4] = {};
  int NT = K >> 5;

  stage128x32(A, Bt, sA[0], sB[0], m0, n0, K, 0, tid);
  __syncthreads();
  for (int kt = 0; kt < NT; ++kt) {
    int cur = kt & 1;
    if (kt + 1 < NT)
      stage128x32(A, Bt, sA[cur ^ 1], sB[cur ^ 1], m0, n0, K, kt + 1, tid);
    bf16x8 af[4], bv[4];
    #pragma unroll
    for (int mt = 0; mt < 4; ++mt)
      af[mt] = *(const bf16x8*)&sA[cur][(wm * 64 + mt * 16 + li) * 32 + g8];
    #pragma unroll
    for (int nt = 0; nt < 4; ++nt)
      bv[nt] = *(const bf16x8*)&sB[cur][(wn * 64 + nt * 16 + li) * 32 + g8];
    #pragma unroll
    for (int mt = 0; mt < 4; ++mt)
      #pragma unroll
      for (int nt = 0; nt < 4; ++nt)
        acc[mt][nt] = mfma16(af[mt], bv[nt], acc[mt][nt]);
    __syncthreads();
  }
  #pragma unroll
  for (int mt = 0; mt < 4; ++mt)
    #pragma unroll
    for (int nt = 0; nt < 4; ++nt)
      #pragma unroll
      for (int j = 0; j < 4; ++j) {
        int row = m0 + wm * 64 + mt * 16 + g * 4 + j;
        int col = n0 + wn * 64 + nt * 16 + li;
        float v = acc[mt][nt][j];
        if (outMode == 0)      ((bf16*)Cv)[(size_t)row * N + col] = (bf16)v;
        else if (outMode == 1) ((bf16*)Cv)[(size_t)col * M + row] = (bf16)v;
        else if (outMode == 2) ((float*)Cv)[(size_t)row * N + col] = v;
        else {  // 3: merged KV
          if (col < 512) ((bf16*)Cv)[(size_t)row * 512 + col] = (bf16)v;
          else           Vtout[(size_t)(col - 512) * M + row] = (bf16)v;
        }
      }
}

// ============== 256x256 8-wave GEMM (round-7 best variant) ==================
template<int RSP>  // 64 for A halves, 32 for B halves
__device__ __forceinline__ void stage_quad(const bf16* __restrict__ G,
                                           bf16* __restrict__ sbuf,
                                           int grow0, int K, int k0, int half, int tid) {
  int w = tid >> 6, lane = tid & 63;
  int rl = lane >> 3;                         // row within the 8-row group
  int col = ((lane & 7) ^ rl) * 8;            // inverse-swizzled SOURCE col (rule #21)
  #pragma unroll
  for (int r = 0; r < 2; ++r) {
    int lr0 = r * 64 + w * 8;                 // multiple of 8, 0..120
    int row0 = (lr0 & (RSP - 1)) + half * RSP + (lr0 / RSP) * 2 * RSP;
    gld16(G + (size_t)(grow0 + row0 + rl) * K + k0 + col,
          sbuf + row0 * 64);                  // wave-uniform linear LDS dest
  }
}

__global__ __launch_bounds__(512, 2) void gemm256(const bf16* __restrict__ A,
                                                  const bf16* __restrict__ Bt,
                                                  void* __restrict__ Cv,
                                                  int M, int N, int K, int outMode) {
  __shared__ bf16 sA[2][256 * 64];
  __shared__ bf16 sB[2][256 * 64];
  int nb = N >> 8;
  int cpx = (int)gridDim.x >> 3;
  int bid = (int)blockIdx.x;
  int swzb = (bid & 7) * cpx + (bid >> 3);
  int bm = swzb / nb, bn = swzb % nb;
  int m0 = bm << 8, n0 = bn << 8;
  int tid = threadIdx.x, lane = tid & 63, w = tid >> 6;
  int li = lane & 15, g = lane >> 4;
  int wm = w >> 2, wn = w & 3;                // 2 x 4 wave grid
  int swz = (li & 7);

  f32x4 acc[8][4] = {};
  bf16x8 af[4][2];
  bf16x8 bv[2][2][2];

  int NT = K >> 6;

  stage_quad<64>(A,  sA[0], m0, K, 0, 0, tid);
  stage_quad<32>(Bt, sB[0], n0, K, 0, 0, tid);
  stage_quad<32>(Bt, sB[0], n0, K, 0, 1, tid);
  stage_quad<64>(A,  sA[0], m0, K, 0, 1, tid);

#define VMW(n) asm volatile("s_waitcnt vmcnt(" #n ")" ::: "memory")
#define SBAR() __builtin_amdgcn_sched_barrier(0)
#define LGKM(n) { asm volatile("s_waitcnt lgkmcnt(" #n ")" ::: "memory"); \
  __builtin_amdgcn_sched_barrier(0); }
#define LOAD_A256(mh) { _Pragma("unroll") for (int mf = 0; mf < 4; ++mf) \
  _Pragma("unroll") for (int ks = 0; ks < 2; ++ks) { \
    int row = wm * 128 + (mh) * 64 + mf * 16 + li; \
    af[mf][ks] = *(const bf16x8*)&sA[cur][row * 64 + ((ks * 4 + g) ^ swz) * 8]; } }
#define LOAD_B256(nh) { _Pragma("unroll") for (int nf = 0; nf < 2; ++nf) \
  _Pragma("unroll") for (int ks = 0; ks < 2; ++ks) { \
    int row = wn * 64 + (nh) * 32 + nf * 16 + li; \
    bv[nh][nf][ks] = *(const bf16x8*)&sB[cur][row * 64 + ((ks * 4 + g) ^ swz) * 8]; } }
#define MFMA_PH(mh, nh) { \
  __builtin_amdgcn_s_setprio(1); \
  _Pragma("unroll") for (int mf = 0; mf < 4; ++mf) \
  _Pragma("unroll") for (int nf = 0; nf < 2; ++nf) \
  _Pragma("unroll") for (int ks = 0; ks < 2; ++ks) \
    acc[(mh) * 4 + mf][(nh) * 2 + nf] = \
      mfma16(af[mf][ks], bv[nh][nf][ks], acc[(mh) * 4 + mf][(nh) * 2 + nf]); \
  __builtin_amdgcn_s_setprio(0); }

  int cur = 0;
  for (int t = 0; t < NT; ++t) {
    int nxt = cur ^ 1;
    bool pre = (t + 1 < NT);
    int k1 = (t + 1) << 6;
    VMW(0);
    barrier_raw();
    if (pre) stage_quad<64>(A, sA[nxt], m0, K, k1, 0, tid);
    LOAD_A256(0); LOAD_B256(0);
    SBAR();
    LOAD_B256(1);
    if (pre) stage_quad<32>(Bt, sB[nxt], n0, K, k1, 0, tid);
    LGKM(4);
    MFMA_PH(0, 0);
    if (pre) stage_quad<32>(Bt, sB[nxt], n0, K, k1, 1, tid);
    LGKM(0);
    MFMA_PH(0, 1);
    LOAD_A256(1);
    if (pre) stage_quad<64>(A, sA[nxt], m0, K, k1, 1, tid);
    LGKM(0);
    MFMA_PH(1, 1);
    MFMA_PH(1, 0);
    cur = nxt;
  }
#undef VMW
#undef SBAR
#undef LGKM
#undef LOAD_A256
#undef LOAD_B256
#undef MFMA_PH

  #pragma unroll
  for (int mi = 0; mi < 8; ++mi)
    #pragma unroll
    for (int ni = 0; ni < 4; ++ni)
      #pragma unroll
      for (int j = 0; j < 4; ++j) {
        int row = m0 + wm * 128 + mi * 16 + g * 4 + j;
        int col = n0 + wn * 64 + ni * 16 + li;
        float v = acc[mi][ni][j];
        if (outMode == 2) ((float*)Cv)[(size_t)row * N + col] = v;
        else              ((bf16*)Cv)[(size_t)row * N + col] = (bf16)v;
      }
}

// ---------------- RoPE in place: X (T x heads*128), interleaved pairs -------
__global__ __launch_bounds__(256) void rope_kernel(bf16* __restrict__ X,
                                                   const int* __restrict__ pos,
                                                   int T, int heads) {
  int idx = blockIdx.x * 256 + threadIdx.x;
  int total = T * heads * 64;
  if (idx >= total) return;
  int i = idx & 63;
  int rest = idx >> 6;
  int hh = rest % heads;
  int t = rest / heads;
  float inv = expf((float)i * (-9.210340371976184f / 64.0f));
  float ang = (float)pos[t] * inv;
  float s, c;
  sincosf(ang, &s, &c);
  bf16* p = X + ((size_t)t * heads + hh) * HD + 2 * i;
  bf16x2 xv = *(const bf16x2*)p;
  float xe = (float)xv[0], xo = (float)xv[1];
  bf16x2 r;
  r[0] = (bf16)(xe * c - xo * s);
  r[1] = (bf16)(xe * s + xo * c);
  *(bf16x2*)p = r;
}

// -------- sliding-window GQA flash attention, 4 heads/block, double-buffered
// Block = 64 q-rows x one kv-group. 8 waves. K/V double-buffered in LDS:
// prefetch tile t+1 (2 gld16/thread), counted VMW(2) waits only tile-t's own
// loads, raw s_barrier publishes (no vmcnt(0) drain of the prefetch), so
// tile-(t+1) loads stay in flight across the whole compute phase.
__global__ __launch_bounds__(512) void attn_kernel(const bf16* __restrict__ Q,
                                                   const bf16* __restrict__ Kb,
                                                   const bf16* __restrict__ Vt,
                                                   const int* __restrict__ pos,
                                                   const int* __restrict__ cu,
                                                   bf16* __restrict__ O, int T, int B) {
  __shared__ bf16 sK[2][32 * 128];    // chunk stored at chunk^(row&7)
  __shared__ bf16 sVt2[2][64 * 64];   // row r: d=2r|2r+1, chunk^(r&7)
  __shared__ bf16 sP[8][16 * 40];     // per-wave P tile
  int bid = blockIdx.x;
  int kvh = bid & (NKV - 1);
  int q0 = (bid >> 2) * 64;
  int tid = threadIdx.x, lane = tid & 63, w = tid >> 6;
  int hh = w & 3, rh = w >> 2;
  int h = kvh * 4 + hh;
  int li = lane & 15, g = lane >> 4, g8 = g * 8;
  int rb0 = q0 + rh * 32;

  int seq_start = 0, seq_end = T;
  for (int b = 0; b < B; ++b) {
    int a = cu[b], e = cu[b + 1];
    if (q0 >= a && q0 < e) { seq_start = a; seq_end = e; }
  }

  bf16x8 qf[2][4];
  #pragma unroll
  for (int grp = 0; grp < 2; ++grp)
    #pragma unroll
    for (int kd = 0; kd < 4; ++kd)
      qf[grp][kd] = *(const bf16x8*)(Q + (size_t)(rb0 + grp * 16 + li) * HIDDEN
                                     + h * HD + kd * 32 + g8);

  int pq[2][4], pmin[2], pmax[2];
  #pragma unroll
  for (int grp = 0; grp < 2; ++grp) {
    #pragma unroll
    for (int j = 0; j < 4; ++j) pq[grp][j] = pos[rb0 + grp * 16 + g * 4 + j];
    pmin[grp] = pos[rb0 + grp * 16];
    pmax[grp] = pos[rb0 + grp * 16 + 15];
  }

  float lsum[2][4] = {};
  f32x4 acc[2][8] = {};
  int kstart = q0 - WINDOW;
  if (kstart < seq_start) kstart = seq_start;
  int kend = q0 + 64;
  if (kend > seq_end) kend = seq_end;
  const float scale = 0.08838834764831845f;
  int nt = (kend - kstart) >> 5;

  // staging addresses (per thread, fixed across tiles except kb)
  int krow = tid >> 4, kc = (tid & 15) ^ (krow & 7);
  int vr = tid >> 3, vc = (tid & 7) ^ (vr & 7);
  int vd = 2 * vr + (vc >> 2), vkey = (vc & 3) * 8;
  int wbase = (tid & ~63) * 8;

#define STAGE(kb_, buf_) { \
  gld16(Kb + (size_t)((kb_) + krow) * (NKV * HD) + kvh * HD + kc * 8, \
        &sK[buf_][wbase]); \
  gld16(Vt + (size_t)(kvh * HD + vd) * T + (kb_) + vkey, \
        &sVt2[buf_][wbase]); }
#define VMW(n) asm volatile("s_waitcnt vmcnt(" #n ")" ::: "memory")

  STAGE(kstart, 0);
  for (int t = 0; t < nt; ++t) {
    int kb = kstart + t * 32;
    int cur = t & 1;
    bool pre = (t + 1 < nt);
    if (pre) { STAGE(kb + 32, cur ^ 1); VMW(2); }
    else     { VMW(0); }
    barrier_raw();                       // publish tile-t (all waves waited own loads)

    int pkf = pos[kb], pkl = pos[kb + 31];
    int pk0 = pos[kb + li], pk1 = pos[kb + 16 + li];
    #pragma unroll
    for (int grp = 0; grp < 2; ++grp) {
      if (pkf > pmax[grp] || pkl < pmin[grp] - WINDOW) continue;  // wave-uniform
      f32x4 s0v = {0.f, 0.f, 0.f, 0.f}, s1v = {0.f, 0.f, 0.f, 0.f};
      #pragma unroll
      for (int kd = 0; kd < 4; ++kd) {
        int c0 = (kd * 4 + g) ^ (li & 7);
        bf16x8 b0 = *(const bf16x8*)&sK[cur][li * 128 + c0 * 8];
        bf16x8 b1 = *(const bf16x8*)&sK[cur][(16 + li) * 128 + c0 * 8];
        s0v = mfma16(qf[grp][kd], b0, s0v);
        s1v = mfma16(qf[grp][kd], b1, s1v);
      }
      bool interior = (pkl <= pmin[grp]) && (pmax[grp] - pkf <= WINDOW);
      if (interior) {
        #pragma unroll
        for (int j = 0; j < 4; ++j) {
          float p0 = __expf(s0v[j] * scale);
          float p1 = __expf(s1v[j] * scale);
          lsum[grp][j] += p0 + p1;
          sP[w][(g * 4 + j) * 40 + li]      = (bf16)p0;
          sP[w][(g * 4 + j) * 40 + 16 + li] = (bf16)p1;
        }
      } else {
        #pragma unroll
        for (int j = 0; j < 4; ++j) {
          int d0 = pq[grp][j] - pk0, d1 = pq[grp][j] - pk1;
          float p0 = (d0 >= 0 && d0 <= WINDOW) ? __expf(s0v[j] * scale) : 0.f;
          float p1 = (d1 >= 0 && d1 <= WINDOW) ? __expf(s1v[j] * scale) : 0.f;
          lsum[grp][j] += p0 + p1;
          sP[w][(g * 4 + j) * 40 + li]      = (bf16)p0;
          sP[w][(g * 4 + j) * 40 + 16 + li] = (bf16)p1;
        }
      }
      bf16x8 pa = *(const bf16x8*)&sP[w][li * 40 + g8];
      #pragma unroll
      for (int dt = 0; dt < 8; ++dt) {
        int d = dt * 16 + li;
        int vr2 = d >> 1;
        int vc2 = ((d & 1) * 4 + g) ^ (vr2 & 7);
        bf16x8 vf = *(const bf16x8*)&sVt2[cur][vr2 * 64 + vc2 * 8];
        acc[grp][dt] = mfma16(pa, vf, acc[grp][dt]);
      }
    }
    barrier_raw();                       // seal reads before next overwrite
  }
#undef STAGE
#undef VMW

  #pragma unroll
  for (int grp = 0; grp < 2; ++grp)
    #pragma unroll
    for (int j = 0; j < 4; ++j) {
      float rs = lsum[grp][j];
      rs += __shfl_xor(rs, 1);
      rs += __shfl_xor(rs, 2);
      rs += __shfl_xor(rs, 4);
      rs += __shfl_xor(rs, 8);
      float invl = 1.0f / rs;
      size_t base = (size_t)(rb0 + grp * 16 + g * 4 + j) * HIDDEN + h * HD;
      #pragma unroll
      for (int dt = 0; dt < 8; ++dt)
        O[base + dt * 16 + li] = (bf16)(acc[grp][dt][j] * invl);
    }
}

// ---------------- launcher --------------------------------------------------
extern "C" void kernel_launch(void* const* d_in, const int* in_sizes, int n_in,
                              void* d_out, int out_size, void* d_ws, size_t ws_size,
                              hipStream_t stream) {
  const float* X  = (const float*)d_in[0];
  const float* qw = (const float*)d_in[1];
  const float* kw = (const float*)d_in[2];
  const float* vw = (const float*)d_in[3];
  const float* ow = (const float*)d_in[4];
  const int* pos = (const int*)d_in[5];
  const int* cu  = (const int*)d_in[6];
  int T = in_sizes[0] / HIDDEN;     // 8192
  int B = in_sizes[6] - 1;          // 4
  float* out = (float*)d_out;

  bf16* ws = (bf16*)d_ws;
  size_t off = 0;
  bf16* Xb    = ws + off; off += (size_t)T * HIDDEN;
  bf16* Qb    = ws + off; off += (size_t)T * HIDDEN;       // Q, then attn out
  bf16* Kb    = ws + off; off += (size_t)T * (NKV * HD);
  bf16* Vt    = ws + off; off += (size_t)T * (NKV * HD);
  bf16* qwT   = ws + off; off += (size_t)HIDDEN * HIDDEN;
  bf16* kvwT  = ws + off; off += (size_t)1024 * HIDDEN;    // [kwT; vwT] stacked
  bf16* owT   = ws + off; off += (size_t)HIDDEN * HIDDEN;

  cast_f32_bf16<<<(T * HIDDEN / 4 + 255) / 256, 256, 0, stream>>>(X, Xb, T * HIDDEN / 4);

  dim3 tb(32, 8);
  transpose_cast<<<dim3(HIDDEN / 32, HIDDEN / 32), tb, 0, stream>>>(qw, qwT, HIDDEN, HIDDEN);
  transpose_cast<<<dim3(512 / 32, HIDDEN / 32), tb, 0, stream>>>(kw, kvwT, HIDDEN, 512);
  transpose_cast<<<dim3(512 / 32, HIDDEN / 32), tb, 0, stream>>>(vw, kvwT + (size_t)512 * HIDDEN, HIDDEN, 512);
  transpose_cast<<<dim3(HIDDEN / 32, HIDDEN / 32), tb, 0, stream>>>(ow, owT, HIDDEN, HIDDEN);

  // Q-projection (bf16 out), grid 256
  gemm256<<<(T / 256) * (HIDDEN / 256), 512, 0, stream>>>(Xb, qwT, Qb, T, HIDDEN, HIDDEN, 0);
  // merged K+V projection: 512 blocks, split epilogue (K row-major, V^T)
  gemm_bt<<<(T / 128) * (1024 / 128), 256, 0, stream>>>(Xb, kvwT, Kb, Vt, T, 1024, HIDDEN, 3);

  // RoPE
  rope_kernel<<<(T * NHEADS * 64 + 255) / 256, 256, 0, stream>>>(Qb, pos, T, NHEADS);
  rope_kernel<<<(T * NKV * 64 + 255) / 256, 256, 0, stream>>>(Kb, pos, T, NKV);

  // attention: 4 heads per block, double-buffered, grid (T/64)*NKV = 512
  attn_kernel<<<(T / 64) * NKV, 512, 0, stream>>>(Qb, Kb, Vt, pos, cu, Qb, T, B);

  // O-projection (fp32 out), grid 256
  gemm256<<<(T / 256) * (HIDDEN / 256), 512, 0, stream>>>(Qb, owT, out, T, HIDDEN, HIDDEN, 2);
}

// Round 13
// 333.134 us; speedup vs baseline: 1.3019x; 1.0076x over previous
//
#include <hip/hip_runtime.h>
#include <hip/hip_bf16.h>
#include <cstdint>
#include <cstddef>

typedef __bf16 bf16;
typedef __bf16 bf16x2 __attribute__((ext_vector_type(2)));
typedef __bf16 bf16x8 __attribute__((ext_vector_type(8)));
typedef float  f32x4  __attribute__((ext_vector_type(4)));

#define HIDDEN 2048
#define NHEADS 16
#define NKV    4
#define HD     128
#define WINDOW 512

// async global->LDS, 16B per lane; LDS dest is wave-uniform base + lane*16
__device__ __forceinline__ void gld16(const void* g, void* s) {
  __builtin_amdgcn_global_load_lds((const __attribute__((address_space(1))) void*)g,
                                   (__attribute__((address_space(3))) void*)s, 16, 0, 0);
}

__device__ __forceinline__ f32x4 mfma16(bf16x8 a, bf16x8 b, f32x4 c) {
  return __builtin_amdgcn_mfma_f32_16x16x32_bf16(a, b, c, 0, 0, 0);
}

__device__ __forceinline__ void barrier_raw() {
  asm volatile("" ::: "memory");
  __builtin_amdgcn_s_barrier();
  asm volatile("" ::: "memory");
}

// ---------------- cast fp32 -> bf16, 4 elems/thread -------------------------
__global__ __launch_bounds__(256) void cast_f32_bf16(const float* __restrict__ in,
                                                     bf16* __restrict__ out, int n4) {
  int i = blockIdx.x * 256 + threadIdx.x;
  if (i >= n4) return;
  f32x4 v = *(const f32x4*)(in + (size_t)i * 4);
  bf16x2 a, b;
  a[0] = (bf16)v[0]; a[1] = (bf16)v[1];
  b[0] = (bf16)v[2]; b[1] = (bf16)v[3];
  *(bf16x2*)(out + (size_t)i * 4)     = a;
  *(bf16x2*)(out + (size_t)i * 4 + 2) = b;
}

// ---------------- transpose+cast: fp32 (R x C) -> bf16 (C x R) --------------
__global__ __launch_bounds__(256) void transpose_cast(const float* __restrict__ in,
                                                      bf16* __restrict__ out, int R, int C) {
  __shared__ float tile[32][33];
  int c0 = blockIdx.x * 32, r0 = blockIdx.y * 32;
  int tx = threadIdx.x, ty = threadIdx.y;
  #pragma unroll
  for (int i = 0; i < 4; ++i)
    tile[ty + i * 8][tx] = in[(size_t)(r0 + ty + i * 8) * C + c0 + tx];
  __syncthreads();
  #pragma unroll
  for (int i = 0; i < 4; ++i)
    out[(size_t)(c0 + ty + i * 8) * R + r0 + tx] = (bf16)tile[tx][ty + i * 8];
}

// ========== 128x128 GEMM (merged K+V projection, outMode 3 splits) ==========
// XCD-grouping swizzle: the nb blocks sharing one A-tile all land on the SAME
// XCD (bid%8 = XCD; swzb packs per-XCD-contiguous ranges) -> A fetched once
// per XCD instead of 8x. One raw barrier per K-tile; VMW(0) waits only own
// tile-kt loads (issued a full compute phase earlier); stage(kt+1) issued
// post-barrier so its latency hides under compute(kt).
__device__ __forceinline__ void stage128x32(const bf16* __restrict__ A,
                                            const bf16* __restrict__ Bt,
                                            bf16* sA, bf16* sB,
                                            int m0, int n0, int K, int kt, int tid) {
  int wbase = tid & ~63;
  #pragma unroll
  for (int r = 0; r < 2; ++r) {
    int e = (r * 256 + tid) * 8;
    int row = e >> 5, col = e & 31;
    gld16(A  + (size_t)(m0 + row) * K + (size_t)kt * 32 + col,
          sA + (size_t)(r * 256 + wbase) * 8);
    gld16(Bt + (size_t)(n0 + row) * K + (size_t)kt * 32 + col,
          sB + (size_t)(r * 256 + wbase) * 8);
  }
}

// outMode: 0 bf16 row-major; 1 bf16 C^T; 2 fp32 row-major;
//          3 merged KV: col<512 -> Cv row-major (N=512), col>=512 -> Vt^T
__global__ __launch_bounds__(256) void gemm_bt(const bf16* __restrict__ A,
                                               const bf16* __restrict__ Bt,
                                               void* __restrict__ Cv,
                                               bf16* __restrict__ Vtout,
                                               int M, int N, int K, int outMode) {
  __shared__ bf16 sA[2][128 * 32];
  __shared__ bf16 sB[2][128 * 32];
  int nb = N >> 7;
  int perx = (int)gridDim.x >> 3;            // grid must be a multiple of 8
  int bid0 = (int)blockIdx.x;
  int swzb = (bid0 & 7) * perx + (bid0 >> 3);
  int bm = swzb / nb, bn = swzb % nb;
  int m0 = bm << 7, n0 = bn << 7;
  int tid = threadIdx.x;
  int lane = tid & 63, w = tid >> 6;
  int li = lane & 15, g = lane >> 4, g8 = g * 8;
  int wm = w >> 1, wn = w & 1;
  f32x4 acc[4][4] = {};
  int NT = K >> 5;

  stage128x32(A, Bt, sA[0], sB[0], m0, n0, K, 0, tid);
  for (int kt = 0; kt < NT; ++kt) {
    int cur = kt & 1;
    asm volatile("s_waitcnt vmcnt(0)" ::: "memory");   // own tile-kt loads
    barrier_raw();                                      // publish to all waves
    if (kt + 1 < NT)
      stage128x32(A, Bt, sA[cur ^ 1], sB[cur ^ 1], m0, n0, K, kt + 1, tid);
    bf16x8 af[4], bv[4];
    #pragma unroll
    for (int mt = 0; mt < 4; ++mt)
      af[mt] = *(const bf16x8*)&sA[cur][(wm * 64 + mt * 16 + li) * 32 + g8];
    #pragma unroll
    for (int nt = 0; nt < 4; ++nt)
      bv[nt] = *(const bf16x8*)&sB[cur][(wn * 64 + nt * 16 + li) * 32 + g8];
    #pragma unroll
    for (int mt = 0; mt < 4; ++mt)
      #pragma unroll
      for (int nt = 0; nt < 4; ++nt)
        acc[mt][nt] = mfma16(af[mt], bv[nt], acc[mt][nt]);
    // no trailing barrier: tile-kt reads complete before their MFMAs issue
    // (compiler lgkmcnt), which precede iter-(kt+1)'s barrier; the stage that
    // overwrites this buffer happens after that barrier.
  }
  #pragma unroll
  for (int mt = 0; mt < 4; ++mt)
    #pragma unroll
    for (int nt = 0; nt < 4; ++nt)
      #pragma unroll
      for (int j = 0; j < 4; ++j) {
        int row = m0 + wm * 64 + mt * 16 + g * 4 + j;
        int col = n0 + wn * 64 + nt * 16 + li;
        float v = acc[mt][nt][j];
        if (outMode == 0)      ((bf16*)Cv)[(size_t)row * N + col] = (bf16)v;
        else if (outMode == 1) ((bf16*)Cv)[(size_t)col * M + row] = (bf16)v;
        else if (outMode == 2) ((float*)Cv)[(size_t)row * N + col] = v;
        else {  // 3: merged KV
          if (col < 512) ((bf16*)Cv)[(size_t)row * 512 + col] = (bf16)v;
          else           Vtout[(size_t)(col - 512) * M + row] = (bf16)v;
        }
      }
}

// ============== 256x256 8-wave GEMM (round-7 best variant) ==================
template<int RSP>  // 64 for A halves, 32 for B halves
__device__ __forceinline__ void stage_quad(const bf16* __restrict__ G,
                                           bf16* __restrict__ sbuf,
                                           int grow0, int K, int k0, int half, int tid) {
  int w = tid >> 6, lane = tid & 63;
  int rl = lane >> 3;                         // row within the 8-row group
  int col = ((lane & 7) ^ rl) * 8;            // inverse-swizzled SOURCE col (rule #21)
  #pragma unroll
  for (int r = 0; r < 2; ++r) {
    int lr0 = r * 64 + w * 8;                 // multiple of 8, 0..120
    int row0 = (lr0 & (RSP - 1)) + half * RSP + (lr0 / RSP) * 2 * RSP;
    gld16(G + (size_t)(grow0 + row0 + rl) * K + k0 + col,
          sbuf + row0 * 64);                  // wave-uniform linear LDS dest
  }
}

__global__ __launch_bounds__(512, 2) void gemm256(const bf16* __restrict__ A,
                                                  const bf16* __restrict__ Bt,
                                                  void* __restrict__ Cv,
                                                  int M, int N, int K, int outMode) {
  __shared__ bf16 sA[2][256 * 64];
  __shared__ bf16 sB[2][256 * 64];
  int nb = N >> 8;
  int cpx = (int)gridDim.x >> 3;
  int bid = (int)blockIdx.x;
  int swzb = (bid & 7) * cpx + (bid >> 3);
  int bm = swzb / nb, bn = swzb % nb;
  int m0 = bm << 8, n0 = bn << 8;
  int tid = threadIdx.x, lane = tid & 63, w = tid >> 6;
  int li = lane & 15, g = lane >> 4;
  int wm = w >> 2, wn = w & 3;                // 2 x 4 wave grid
  int swz = (li & 7);

  f32x4 acc[8][4] = {};
  bf16x8 af[4][2];
  bf16x8 bv[2][2][2];

  int NT = K >> 6;

  stage_quad<64>(A,  sA[0], m0, K, 0, 0, tid);
  stage_quad<32>(Bt, sB[0], n0, K, 0, 0, tid);
  stage_quad<32>(Bt, sB[0], n0, K, 0, 1, tid);
  stage_quad<64>(A,  sA[0], m0, K, 0, 1, tid);

#define VMW(n) asm volatile("s_waitcnt vmcnt(" #n ")" ::: "memory")
#define SBAR() __builtin_amdgcn_sched_barrier(0)
#define LGKM(n) { asm volatile("s_waitcnt lgkmcnt(" #n ")" ::: "memory"); \
  __builtin_amdgcn_sched_barrier(0); }
#define LOAD_A256(mh) { _Pragma("unroll") for (int mf = 0; mf < 4; ++mf) \
  _Pragma("unroll") for (int ks = 0; ks < 2; ++ks) { \
    int row = wm * 128 + (mh) * 64 + mf * 16 + li; \
    af[mf][ks] = *(const bf16x8*)&sA[cur][row * 64 + ((ks * 4 + g) ^ swz) * 8]; } }
#define LOAD_B256(nh) { _Pragma("unroll") for (int nf = 0; nf < 2; ++nf) \
  _Pragma("unroll") for (int ks = 0; ks < 2; ++ks) { \
    int row = wn * 64 + (nh) * 32 + nf * 16 + li; \
    bv[nh][nf][ks] = *(const bf16x8*)&sB[cur][row * 64 + ((ks * 4 + g) ^ swz) * 8]; } }
#define MFMA_PH(mh, nh) { \
  __builtin_amdgcn_s_setprio(1); \
  _Pragma("unroll") for (int mf = 0; mf < 4; ++mf) \
  _Pragma("unroll") for (int nf = 0; nf < 2; ++nf) \
  _Pragma("unroll") for (int ks = 0; ks < 2; ++ks) \
    acc[(mh) * 4 + mf][(nh) * 2 + nf] = \
      mfma16(af[mf][ks], bv[nh][nf][ks], acc[(mh) * 4 + mf][(nh) * 2 + nf]); \
  __builtin_amdgcn_s_setprio(0); }

  int cur = 0;
  for (int t = 0; t < NT; ++t) {
    int nxt = cur ^ 1;
    bool pre = (t + 1 < NT);
    int k1 = (t + 1) << 6;
    VMW(0);
    barrier_raw();
    if (pre) stage_quad<64>(A, sA[nxt], m0, K, k1, 0, tid);
    LOAD_A256(0); LOAD_B256(0);
    SBAR();
    LOAD_B256(1);
    if (pre) stage_quad<32>(Bt, sB[nxt], n0, K, k1, 0, tid);
    LGKM(4);
    MFMA_PH(0, 0);
    if (pre) stage_quad<32>(Bt, sB[nxt], n0, K, k1, 1, tid);
    LGKM(0);
    MFMA_PH(0, 1);
    LOAD_A256(1);
    if (pre) stage_quad<64>(A, sA[nxt], m0, K, k1, 1, tid);
    LGKM(0);
    MFMA_PH(1, 1);
    MFMA_PH(1, 0);
    cur = nxt;
  }
#undef VMW
#undef SBAR
#undef LGKM
#undef LOAD_A256
#undef LOAD_B256
#undef MFMA_PH

  #pragma unroll
  for (int mi = 0; mi < 8; ++mi)
    #pragma unroll
    for (int ni = 0; ni < 4; ++ni)
      #pragma unroll
      for (int j = 0; j < 4; ++j) {
        int row = m0 + wm * 128 + mi * 16 + g * 4 + j;
        int col = n0 + wn * 64 + ni * 16 + li;
        float v = acc[mi][ni][j];
        if (outMode == 2) ((float*)Cv)[(size_t)row * N + col] = v;
        else              ((bf16*)Cv)[(size_t)row * N + col] = (bf16)v;
      }
}

// ---------------- RoPE in place: X (T x heads*128), interleaved pairs -------
__global__ __launch_bounds__(256) void rope_kernel(bf16* __restrict__ X,
                                                   const int* __restrict__ pos,
                                                   int T, int heads) {
  int idx = blockIdx.x * 256 + threadIdx.x;
  int total = T * heads * 64;
  if (idx >= total) return;
  int i = idx & 63;
  int rest = idx >> 6;
  int hh = rest % heads;
  int t = rest / heads;
  float inv = expf((float)i * (-9.210340371976184f / 64.0f));
  float ang = (float)pos[t] * inv;
  float s, c;
  sincosf(ang, &s, &c);
  bf16* p = X + ((size_t)t * heads + hh) * HD + 2 * i;
  bf16x2 xv = *(const bf16x2*)p;
  float xe = (float)xv[0], xo = (float)xv[1];
  bf16x2 r;
  r[0] = (bf16)(xe * c - xo * s);
  r[1] = (bf16)(xe * s + xo * c);
  *(bf16x2*)p = r;
}

// -------- sliding-window GQA flash attention, 4 heads/block, double-buffered
// ONE raw barrier per tile: VMW(0) waits only this wave's 2 tile-t loads
// (issued a full compute phase earlier), barrier publishes + seals the
// previous compute's buffer reads, then stage(t+1) + compute(t).
// Block order: kvh-major with XCD-contiguous q-ranges (same-XCD blocks share
// overlapping K/V windows -> L2 locality).
__global__ __launch_bounds__(512) void attn_kernel(const bf16* __restrict__ Q,
                                                   const bf16* __restrict__ Kb,
                                                   const bf16* __restrict__ Vt,
                                                   const int* __restrict__ pos,
                                                   const int* __restrict__ cu,
                                                   bf16* __restrict__ O, int T, int B) {
  __shared__ bf16 sK[2][32 * 128];    // chunk stored at chunk^(row&7)
  __shared__ bf16 sVt2[2][64 * 64];   // row r: d=2r|2r+1, chunk^(r&7)
  __shared__ bf16 sP[8][16 * 40];     // per-wave P tile
  int bid = blockIdx.x;
  int nqb = T >> 6;                    // q-blocks per kv head (multiple of 8)
  int kvh = bid / nqb;
  int u   = bid % nqb;
  int qb  = (u & 7) * (nqb >> 3) + (u >> 3);   // XCD-contiguous q-ranges
  int q0 = qb * 64;
  int tid = threadIdx.x, lane = tid & 63, w = tid >> 6;
  int hh = w & 3, rh = w >> 2;
  int h = kvh * 4 + hh;
  int li = lane & 15, g = lane >> 4, g8 = g * 8;
  int rb0 = q0 + rh * 32;

  int seq_start = 0, seq_end = T;
  for (int b = 0; b < B; ++b) {
    int a = cu[b], e = cu[b + 1];
    if (q0 >= a && q0 < e) { seq_start = a; seq_end = e; }
  }

  bf16x8 qf[2][4];
  #pragma unroll
  for (int grp = 0; grp < 2; ++grp)
    #pragma unroll
    for (int kd = 0; kd < 4; ++kd)
      qf[grp][kd] = *(const bf16x8*)(Q + (size_t)(rb0 + grp * 16 + li) * HIDDEN
                                     + h * HD + kd * 32 + g8);

  int pq[2][4], pmin[2], pmax[2];
  #pragma unroll
  for (int grp = 0; grp < 2; ++grp) {
    #pragma unroll
    for (int j = 0; j < 4; ++j) pq[grp][j] = pos[rb0 + grp * 16 + g * 4 + j];
    pmin[grp] = pos[rb0 + grp * 16];
    pmax[grp] = pos[rb0 + grp * 16 + 15];
  }

  float lsum[2][4] = {};
  f32x4 acc[2][8] = {};
  int kstart = q0 - WINDOW;
  if (kstart < seq_start) kstart = seq_start;
  int kend = q0 + 64;
  if (kend > seq_end) kend = seq_end;
  const float scale = 0.08838834764831845f;
  int nt = (kend - kstart) >> 5;

  // staging addresses (per thread, fixed across tiles except kb)
  int krow = tid >> 4, kc = (tid & 15) ^ (krow & 7);
  int vr = tid >> 3, vc = (tid & 7) ^ (vr & 7);
  int vd = 2 * vr + (vc >> 2), vkey = (vc & 3) * 8;
  int wbase = (tid & ~63) * 8;

#define STAGE(kb_, buf_) { \
  gld16(Kb + (size_t)((kb_) + krow) * (NKV * HD) + kvh * HD + kc * 8, \
        &sK[buf_][wbase]); \
  gld16(Vt + (size_t)(kvh * HD + vd) * T + (kb_) + vkey, \
        &sVt2[buf_][wbase]); }
#define VMW(n) asm volatile("s_waitcnt vmcnt(" #n ")" ::: "memory")

  STAGE(kstart, 0);
  for (int t = 0; t < nt; ++t) {
    int kb = kstart + t * 32;
    int cur = t & 1;
    VMW(0);                            // own 2 loads of tile t (prefetched)
    barrier_raw();                     // publish tile t; seal prev buffer reads
    if (t + 1 < nt) STAGE(kb + 32, cur ^ 1);

    int pkf = pos[kb], pkl = pos[kb + 31];
    int pk0 = pos[kb + li], pk1 = pos[kb + 16 + li];
    #pragma unroll
    for (int grp = 0; grp < 2; ++grp) {
      if (pkf > pmax[grp] || pkl < pmin[grp] - WINDOW) continue;  // wave-uniform
      f32x4 s0v = {0.f, 0.f, 0.f, 0.f}, s1v = {0.f, 0.f, 0.f, 0.f};
      #pragma unroll
      for (int kd = 0; kd < 4; ++kd) {
        int c0 = (kd * 4 + g) ^ (li & 7);
        bf16x8 b0 = *(const bf16x8*)&sK[cur][li * 128 + c0 * 8];
        bf16x8 b1 = *(const bf16x8*)&sK[cur][(16 + li) * 128 + c0 * 8];
        s0v = mfma16(qf[grp][kd], b0, s0v);
        s1v = mfma16(qf[grp][kd], b1, s1v);
      }
      bool interior = (pkl <= pmin[grp]) && (pmax[grp] - pkf <= WINDOW);
      if (interior) {
        #pragma unroll
        for (int j = 0; j < 4; ++j) {
          float p0 = __expf(s0v[j] * scale);
          float p1 = __expf(s1v[j] * scale);
          lsum[grp][j] += p0 + p1;
          sP[w][(g * 4 + j) * 40 + li]      = (bf16)p0;
          sP[w][(g * 4 + j) * 40 + 16 + li] = (bf16)p1;
        }
      } else {
        #pragma unroll
        for (int j = 0; j < 4; ++j) {
          int d0 = pq[grp][j] - pk0, d1 = pq[grp][j] - pk1;
          float p0 = (d0 >= 0 && d0 <= WINDOW) ? __expf(s0v[j] * scale) : 0.f;
          float p1 = (d1 >= 0 && d1 <= WINDOW) ? __expf(s1v[j] * scale) : 0.f;
          lsum[grp][j] += p0 + p1;
          sP[w][(g * 4 + j) * 40 + li]      = (bf16)p0;
          sP[w][(g * 4 + j) * 40 + 16 + li] = (bf16)p1;
        }
      }
      bf16x8 pa = *(const bf16x8*)&sP[w][li * 40 + g8];
      #pragma unroll
      for (int dt = 0; dt < 8; ++dt) {
        int d = dt * 16 + li;
        int vr2 = d >> 1;
        int vc2 = ((d & 1) * 4 + g) ^ (vr2 & 7);
        bf16x8 vf = *(const bf16x8*)&sVt2[cur][vr2 * 64 + vc2 * 8];
        acc[grp][dt] = mfma16(pa, vf, acc[grp][dt]);
      }
    }
  }
#undef STAGE
#undef VMW

  #pragma unroll
  for (int grp = 0; grp < 2; ++grp)
    #pragma unroll
    for (int j = 0; j < 4; ++j) {
      float rs = lsum[grp][j];
      rs += __shfl_xor(rs, 1);
      rs += __shfl_xor(rs, 2);
      rs += __shfl_xor(rs, 4);
      rs += __shfl_xor(rs, 8);
      float invl = 1.0f / rs;
      size_t base = (size_t)(rb0 + grp * 16 + g * 4 + j) * HIDDEN + h * HD;
      #pragma unroll
      for (int dt = 0; dt < 8; ++dt)
        O[base + dt * 16 + li] = (bf16)(acc[grp][dt][j] * invl);
    }
}

// ---------------- launcher --------------------------------------------------
extern "C" void kernel_launch(void* const* d_in, const int* in_sizes, int n_in,
                              void* d_out, int out_size, void* d_ws, size_t ws_size,
                              hipStream_t stream) {
  const float* X  = (const float*)d_in[0];
  const float* qw = (const float*)d_in[1];
  const float* kw = (const float*)d_in[2];
  const float* vw = (const float*)d_in[3];
  const float* ow = (const float*)d_in[4];
  const int* pos = (const int*)d_in[5];
  const int* cu  = (const int*)d_in[6];
  int T = in_sizes[0] / HIDDEN;     // 8192
  int B = in_sizes[6] - 1;          // 4
  float* out = (float*)d_out;

  bf16* ws = (bf16*)d_ws;
  size_t off = 0;
  bf16* Xb    = ws + off; off += (size_t)T * HIDDEN;
  bf16* Qb    = ws + off; off += (size_t)T * HIDDEN;       // Q, then attn out
  bf16* Kb    = ws + off; off += (size_t)T * (NKV * HD);
  bf16* Vt    = ws + off; off += (size_t)T * (NKV * HD);
  bf16* qwT   = ws + off; off += (size_t)HIDDEN * HIDDEN;
  bf16* kvwT  = ws + off; off += (size_t)1024 * HIDDEN;    // [kwT; vwT] stacked
  bf16* owT   = ws + off; off += (size_t)HIDDEN * HIDDEN;

  cast_f32_bf16<<<(T * HIDDEN / 4 + 255) / 256, 256, 0, stream>>>(X, Xb, T * HIDDEN / 4);

  dim3 tb(32, 8);
  transpose_cast<<<dim3(HIDDEN / 32, HIDDEN / 32), tb, 0, stream>>>(qw, qwT, HIDDEN, HIDDEN);
  transpose_cast<<<dim3(512 / 32, HIDDEN / 32), tb, 0, stream>>>(kw, kvwT, HIDDEN, 512);
  transpose_cast<<<dim3(512 / 32, HIDDEN / 32), tb, 0, stream>>>(vw, kvwT + (size_t)512 * HIDDEN, HIDDEN, 512);
  transpose_cast<<<dim3(HIDDEN / 32, HIDDEN / 32), tb, 0, stream>>>(ow, owT, HIDDEN, HIDDEN);

  // Q-projection (bf16 out), grid 256
  gemm256<<<(T / 256) * (HIDDEN / 256), 512, 0, stream>>>(Xb, qwT, Qb, T, HIDDEN, HIDDEN, 0);
  // merged K+V projection: 512 blocks, XCD-grouped, split epilogue
  gemm_bt<<<(T / 128) * (1024 / 128), 256, 0, stream>>>(Xb, kvwT, Kb, Vt, T, 1024, HIDDEN, 3);

  // RoPE
  rope_kernel<<<(T * NHEADS * 64 + 255) / 256, 256, 0, stream>>>(Qb, pos, T, NHEADS);
  rope_kernel<<<(T * NKV * 64 + 255) / 256, 256, 0, stream>>>(Kb, pos, T, NKV);

  // attention: 4 heads per block, double-buffered, grid (T/64)*NKV = 512
  attn_kernel<<<(T / 64) * NKV, 512, 0, stream>>>(Qb, Kb, Vt, pos, cu, Qb, T, B);

  // O-projection (fp32 out), grid 256
  gemm256<<<(T / 256) * (HIDDEN / 256), 512, 0, stream>>>(Qb, owT, out, T, HIDDEN, HIDDEN, 2);
}

// Round 14
// 320.483 us; speedup vs baseline: 1.3533x; 1.0395x over previous
//
#include <hip/hip_runtime.h>
#include <hip/hip_bf16.h>
#include <cstdint>
#include <cstddef>

typedef __bf16 bf16;
typedef __bf16 bf16x2 __attribute__((ext_vector_type(2)));
typedef __bf16 bf16x8 __attribute__((ext_vector_type(8)));
typedef float  f32x4  __attribute__((ext_vector_type(4)));

#define HIDDEN 2048
#define NHEADS 16
#define NKV    4
#define HD     128
#define WINDOW 512

// async global->LDS, 16B per lane; LDS dest is wave-uniform base + lane*16
__device__ __forceinline__ void gld16(const void* g, void* s) {
  __builtin_amdgcn_global_load_lds((const __attribute__((address_space(1))) void*)g,
                                   (__attribute__((address_space(3))) void*)s, 16, 0, 0);
}

__device__ __forceinline__ f32x4 mfma16(bf16x8 a, bf16x8 b, f32x4 c) {
  return __builtin_amdgcn_mfma_f32_16x16x32_bf16(a, b, c, 0, 0, 0);
}

__device__ __forceinline__ void barrier_raw() {
  asm volatile("" ::: "memory");
  __builtin_amdgcn_s_barrier();
  asm volatile("" ::: "memory");
}

// ---------------- cast fp32 -> bf16, 4 elems/thread -------------------------
__global__ __launch_bounds__(256) void cast_f32_bf16(const float* __restrict__ in,
                                                     bf16* __restrict__ out, int n4) {
  int i = blockIdx.x * 256 + threadIdx.x;
  if (i >= n4) return;
  f32x4 v = *(const f32x4*)(in + (size_t)i * 4);
  bf16x2 a, b;
  a[0] = (bf16)v[0]; a[1] = (bf16)v[1];
  b[0] = (bf16)v[2]; b[1] = (bf16)v[3];
  *(bf16x2*)(out + (size_t)i * 4)     = a;
  *(bf16x2*)(out + (size_t)i * 4 + 2) = b;
}

// ---------------- transpose+cast: fp32 (R x C) -> bf16 (C x R) --------------
__global__ __launch_bounds__(256) void transpose_cast(const float* __restrict__ in,
                                                      bf16* __restrict__ out, int R, int C) {
  __shared__ float tile[32][33];
  int c0 = blockIdx.x * 32, r0 = blockIdx.y * 32;
  int tx = threadIdx.x, ty = threadIdx.y;
  #pragma unroll
  for (int i = 0; i < 4; ++i)
    tile[ty + i * 8][tx] = in[(size_t)(r0 + ty + i * 8) * C + c0 + tx];
  __syncthreads();
  #pragma unroll
  for (int i = 0; i < 4; ++i)
    out[(size_t)(c0 + ty + i * 8) * R + r0 + tx] = (bf16)tile[tx][ty + i * 8];
}

// ========== 128x128 GEMM (merged K+V projection, outMode 3 splits) ==========
__device__ __forceinline__ void stage128x32(const bf16* __restrict__ A,
                                            const bf16* __restrict__ Bt,
                                            bf16* sA, bf16* sB,
                                            int m0, int n0, int K, int kt, int tid) {
  int wbase = tid & ~63;
  #pragma unroll
  for (int r = 0; r < 2; ++r) {
    int e = (r * 256 + tid) * 8;
    int row = e >> 5, col = e & 31;
    gld16(A  + (size_t)(m0 + row) * K + (size_t)kt * 32 + col,
          sA + (size_t)(r * 256 + wbase) * 8);
    gld16(Bt + (size_t)(n0 + row) * K + (size_t)kt * 32 + col,
          sB + (size_t)(r * 256 + wbase) * 8);
  }
}

// outMode: 0 bf16 row-major; 1 bf16 C^T; 2 fp32 row-major;
//          3 merged KV: col<512 -> Cv row-major (N=512), col>=512 -> Vt^T
__global__ __launch_bounds__(256) void gemm_bt(const bf16* __restrict__ A,
                                               const bf16* __restrict__ Bt,
                                               void* __restrict__ Cv,
                                               bf16* __restrict__ Vtout,
                                               int M, int N, int K, int outMode) {
  __shared__ bf16 sA[2][128 * 32];
  __shared__ bf16 sB[2][128 * 32];
  int nb = N >> 7;
  int perx = (int)gridDim.x >> 3;
  int bid0 = (int)blockIdx.x;
  int swzb = (bid0 & 7) * perx + (bid0 >> 3);
  int bm = swzb / nb, bn = swzb % nb;
  int m0 = bm << 7, n0 = bn << 7;
  int tid = threadIdx.x;
  int lane = tid & 63, w = tid >> 6;
  int li = lane & 15, g = lane >> 4, g8 = g * 8;
  int wm = w >> 1, wn = w & 1;
  f32x4 acc[4][4] = {};
  int NT = K >> 5;

  stage128x32(A, Bt, sA[0], sB[0], m0, n0, K, 0, tid);
  for (int kt = 0; kt < NT; ++kt) {
    int cur = kt & 1;
    asm volatile("s_waitcnt vmcnt(0)" ::: "memory");
    barrier_raw();
    if (kt + 1 < NT)
      stage128x32(A, Bt, sA[cur ^ 1], sB[cur ^ 1], m0, n0, K, kt + 1, tid);
    bf16x8 af[4], bv[4];
    #pragma unroll
    for (int mt = 0; mt < 4; ++mt)
      af[mt] = *(const bf16x8*)&sA[cur][(wm * 64 + mt * 16 + li) * 32 + g8];
    #pragma unroll
    for (int nt = 0; nt < 4; ++nt)
      bv[nt] = *(const bf16x8*)&sB[cur][(wn * 64 + nt * 16 + li) * 32 + g8];
    #pragma unroll
    for (int mt = 0; mt < 4; ++mt)
      #pragma unroll
      for (int nt = 0; nt < 4; ++nt)
        acc[mt][nt] = mfma16(af[mt], bv[nt], acc[mt][nt]);
  }
  #pragma unroll
  for (int mt = 0; mt < 4; ++mt)
    #pragma unroll
    for (int nt = 0; nt < 4; ++nt)
      #pragma unroll
      for (int j = 0; j < 4; ++j) {
        int row = m0 + wm * 64 + mt * 16 + g * 4 + j;
        int col = n0 + wn * 64 + nt * 16 + li;
        float v = acc[mt][nt][j];
        if (outMode == 0)      ((bf16*)Cv)[(size_t)row * N + col] = (bf16)v;
        else if (outMode == 1) ((bf16*)Cv)[(size_t)col * M + row] = (bf16)v;
        else if (outMode == 2) ((float*)Cv)[(size_t)row * N + col] = v;
        else {
          if (col < 512) ((bf16*)Cv)[(size_t)row * 512 + col] = (bf16)v;
          else           Vtout[(size_t)(col - 512) * M + row] = (bf16)v;
        }
      }
}

// ============== 256x256 8-wave GEMM (round-7 best variant) ==================
template<int RSP>  // 64 for A halves, 32 for B halves
__device__ __forceinline__ void stage_quad(const bf16* __restrict__ G,
                                           bf16* __restrict__ sbuf,
                                           int grow0, int K, int k0, int half, int tid) {
  int w = tid >> 6, lane = tid & 63;
  int rl = lane >> 3;
  int col = ((lane & 7) ^ rl) * 8;            // inverse-swizzled SOURCE col (rule #21)
  #pragma unroll
  for (int r = 0; r < 2; ++r) {
    int lr0 = r * 64 + w * 8;
    int row0 = (lr0 & (RSP - 1)) + half * RSP + (lr0 / RSP) * 2 * RSP;
    gld16(G + (size_t)(grow0 + row0 + rl) * K + k0 + col,
          sbuf + row0 * 64);
  }
}

__global__ __launch_bounds__(512, 2) void gemm256(const bf16* __restrict__ A,
                                                  const bf16* __restrict__ Bt,
                                                  void* __restrict__ Cv,
                                                  int M, int N, int K, int outMode) {
  __shared__ bf16 sA[2][256 * 64];
  __shared__ bf16 sB[2][256 * 64];
  int nb = N >> 8;
  int cpx = (int)gridDim.x >> 3;
  int bid = (int)blockIdx.x;
  int swzb = (bid & 7) * cpx + (bid >> 3);
  int bm = swzb / nb, bn = swzb % nb;
  int m0 = bm << 8, n0 = bn << 8;
  int tid = threadIdx.x, lane = tid & 63, w = tid >> 6;
  int li = lane & 15, g = lane >> 4;
  int wm = w >> 2, wn = w & 3;
  int swz = (li & 7);

  f32x4 acc[8][4] = {};
  bf16x8 af[4][2];
  bf16x8 bv[2][2][2];

  int NT = K >> 6;

  stage_quad<64>(A,  sA[0], m0, K, 0, 0, tid);
  stage_quad<32>(Bt, sB[0], n0, K, 0, 0, tid);
  stage_quad<32>(Bt, sB[0], n0, K, 0, 1, tid);
  stage_quad<64>(A,  sA[0], m0, K, 0, 1, tid);

#define VMW(n) asm volatile("s_waitcnt vmcnt(" #n ")" ::: "memory")
#define SBAR() __builtin_amdgcn_sched_barrier(0)
#define LGKM(n) { asm volatile("s_waitcnt lgkmcnt(" #n ")" ::: "memory"); \
  __builtin_amdgcn_sched_barrier(0); }
#define LOAD_A256(mh) { _Pragma("unroll") for (int mf = 0; mf < 4; ++mf) \
  _Pragma("unroll") for (int ks = 0; ks < 2; ++ks) { \
    int row = wm * 128 + (mh) * 64 + mf * 16 + li; \
    af[mf][ks] = *(const bf16x8*)&sA[cur][row * 64 + ((ks * 4 + g) ^ swz) * 8]; } }
#define LOAD_B256(nh) { _Pragma("unroll") for (int nf = 0; nf < 2; ++nf) \
  _Pragma("unroll") for (int ks = 0; ks < 2; ++ks) { \
    int row = wn * 64 + (nh) * 32 + nf * 16 + li; \
    bv[nh][nf][ks] = *(const bf16x8*)&sB[cur][row * 64 + ((ks * 4 + g) ^ swz) * 8]; } }
#define MFMA_PH(mh, nh) { \
  __builtin_amdgcn_s_setprio(1); \
  _Pragma("unroll") for (int mf = 0; mf < 4; ++mf) \
  _Pragma("unroll") for (int nf = 0; nf < 2; ++nf) \
  _Pragma("unroll") for (int ks = 0; ks < 2; ++ks) \
    acc[(mh) * 4 + mf][(nh) * 2 + nf] = \
      mfma16(af[mf][ks], bv[nh][nf][ks], acc[(mh) * 4 + mf][(nh) * 2 + nf]); \
  __builtin_amdgcn_s_setprio(0); }

  int cur = 0;
  for (int t = 0; t < NT; ++t) {
    int nxt = cur ^ 1;
    bool pre = (t + 1 < NT);
    int k1 = (t + 1) << 6;
    VMW(0);
    barrier_raw();
    if (pre) stage_quad<64>(A, sA[nxt], m0, K, k1, 0, tid);
    LOAD_A256(0); LOAD_B256(0);
    SBAR();
    LOAD_B256(1);
    if (pre) stage_quad<32>(Bt, sB[nxt], n0, K, k1, 0, tid);
    LGKM(4);
    MFMA_PH(0, 0);
    if (pre) stage_quad<32>(Bt, sB[nxt], n0, K, k1, 1, tid);
    LGKM(0);
    MFMA_PH(0, 1);
    LOAD_A256(1);
    if (pre) stage_quad<64>(A, sA[nxt], m0, K, k1, 1, tid);
    LGKM(0);
    MFMA_PH(1, 1);
    MFMA_PH(1, 0);
    cur = nxt;
  }
#undef VMW
#undef SBAR
#undef LGKM
#undef LOAD_A256
#undef LOAD_B256
#undef MFMA_PH

  #pragma unroll
  for (int mi = 0; mi < 8; ++mi)
    #pragma unroll
    for (int ni = 0; ni < 4; ++ni)
      #pragma unroll
      for (int j = 0; j < 4; ++j) {
        int row = m0 + wm * 128 + mi * 16 + g * 4 + j;
        int col = n0 + wn * 64 + ni * 16 + li;
        float v = acc[mi][ni][j];
        if (outMode == 2) ((float*)Cv)[(size_t)row * N + col] = v;
        else              ((bf16*)Cv)[(size_t)row * N + col] = (bf16)v;
      }
}

// ---------------- fused RoPE (Q then K regions), interleaved pairs ----------
__global__ __launch_bounds__(256) void rope_both(bf16* __restrict__ Qb,
                                                 bf16* __restrict__ Kb,
                                                 const int* __restrict__ pos, int T) {
  int idx = blockIdx.x * 256 + threadIdx.x;
  int total_q = T * NHEADS * 64;
  int total   = total_q + T * NKV * 64;
  if (idx >= total) return;
  bf16* X; int heads, local;
  if (idx < total_q) { X = Qb; heads = NHEADS; local = idx; }
  else               { X = Kb; heads = NKV;    local = idx - total_q; }
  int i = local & 63;
  int rest = local >> 6;
  int hh = rest % heads;
  int t = rest / heads;
  float inv = expf((float)i * (-9.210340371976184f / 64.0f));
  float ang = (float)pos[t] * inv;
  float s, c;
  sincosf(ang, &s, &c);
  bf16* p = X + ((size_t)t * heads + hh) * HD + 2 * i;
  bf16x2 xv = *(const bf16x2*)p;
  float xe = (float)xv[0], xo = (float)xv[1];
  bf16x2 r;
  r[0] = (bf16)(xe * c - xo * s);
  r[1] = (bf16)(xe * s + xo * c);
  *(bf16x2*)p = r;
}

// -------- sliding-window GQA flash attention, 4 heads/block, KVBLK=64 -------
// One stage (4 gld16/thread) + one VMW(0)+barrier per 64 keys; inner loop
// walks the two 32-key halves. K LDS [64 key][128 d] chunk^(key&7);
// V LDS [128 d][64 key] chunk^(d&7); both staged linear-dest with
// inverse-swizzled global source (rule #21).
__global__ __launch_bounds__(512) void attn_kernel(const bf16* __restrict__ Q,
                                                   const bf16* __restrict__ Kb,
                                                   const bf16* __restrict__ Vt,
                                                   const int* __restrict__ pos,
                                                   const int* __restrict__ cu,
                                                   bf16* __restrict__ O, int T, int B) {
  __shared__ bf16 sK[2][64 * 128];    // 32 KB
  __shared__ bf16 sV[2][128 * 64];    // 32 KB
  __shared__ bf16 sP[8][16 * 40];     // 10 KB
  int bid = blockIdx.x;
  int nqb = T >> 6;
  int kvh = bid / nqb;
  int u   = bid % nqb;
  int qb  = (u & 7) * (nqb >> 3) + (u >> 3);   // XCD-contiguous q-ranges
  int q0 = qb * 64;
  int tid = threadIdx.x, lane = tid & 63, w = tid >> 6;
  int hh = w & 3, rh = w >> 2;
  int h = kvh * 4 + hh;
  int li = lane & 15, g = lane >> 4, g8 = g * 8;
  int rb0 = q0 + rh * 32;

  int seq_start = 0, seq_end = T;
  for (int b = 0; b < B; ++b) {
    int a = cu[b], e = cu[b + 1];
    if (q0 >= a && q0 < e) { seq_start = a; seq_end = e; }
  }

  bf16x8 qf[2][4];
  #pragma unroll
  for (int grp = 0; grp < 2; ++grp)
    #pragma unroll
    for (int kd = 0; kd < 4; ++kd)
      qf[grp][kd] = *(const bf16x8*)(Q + (size_t)(rb0 + grp * 16 + li) * HIDDEN
                                     + h * HD + kd * 32 + g8);

  int pq[2][4], pmin[2], pmax[2];
  #pragma unroll
  for (int grp = 0; grp < 2; ++grp) {
    #pragma unroll
    for (int j = 0; j < 4; ++j) pq[grp][j] = pos[rb0 + grp * 16 + g * 4 + j];
    pmin[grp] = pos[rb0 + grp * 16];
    pmax[grp] = pos[rb0 + grp * 16 + 15];
  }

  float lsum[2][4] = {};
  f32x4 acc[2][8] = {};
  int kstart = q0 - WINDOW;
  if (kstart < seq_start) kstart = seq_start;
  int kend = q0 + 64;
  if (kend > seq_end) kend = seq_end;
  const float scale = 0.08838834764831845f;
  int nt = (kend - kstart) >> 6;              // span is a multiple of 64

  // staging patterns (2 K-chunks + 2 V-chunks per thread per 64-key tile)
  // K: chunk n in [0,1024): key=n>>4, dst-chunk=n&15, src col=(dst^key&7)*8
  // V: chunk n in [0,1024): d=n>>3,  dst-chunk=n&7,  src key=(dst^d&7)*8
#define STAGE(kb_, buf_) { \
  _Pragma("unroll") for (int r = 0; r < 2; ++r) { \
    int n = r * 512 + tid; \
    int krow = n >> 4, kc = (n & 15) ^ (krow & 7); \
    gld16(Kb + (size_t)((kb_) + krow) * (NKV * HD) + kvh * HD + kc * 8, \
          &sK[buf_][(size_t)(r * 512 + (tid & ~63)) * 8]); \
    int vd = n >> 3, vc = (n & 7) ^ (vd & 7); \
    gld16(Vt + (size_t)(kvh * HD + vd) * T + (kb_) + vc * 8, \
          &sV[buf_][(size_t)(r * 512 + (tid & ~63)) * 8]); } }
#define VMW(n) asm volatile("s_waitcnt vmcnt(" #n ")" ::: "memory")

  STAGE(kstart, 0);
  for (int t = 0; t < nt; ++t) {
    int kb0 = kstart + t * 64;
    int cur = t & 1;
    VMW(0);                            // own 4 loads of tile t (prefetched)
    barrier_raw();                     // publish tile t; seal prev buffer reads
    if (t + 1 < nt) STAGE(kb0 + 64, cur ^ 1);

    #pragma unroll
    for (int hhalf = 0; hhalf < 2; ++hhalf) {
      int kb = kb0 + hhalf * 32;
      int pkf = pos[kb], pkl = pos[kb + 31];
      int pk0 = pos[kb + li], pk1 = pos[kb + 16 + li];
      #pragma unroll
      for (int grp = 0; grp < 2; ++grp) {
        if (pkf > pmax[grp] || pkl < pmin[grp] - WINDOW) continue;  // wave-uniform
        f32x4 s0v = {0.f, 0.f, 0.f, 0.f}, s1v = {0.f, 0.f, 0.f, 0.f};
        #pragma unroll
        for (int kd = 0; kd < 4; ++kd) {
          int c0 = (kd * 4 + g) ^ (li & 7);
          bf16x8 b0 = *(const bf16x8*)&sK[cur][(hhalf * 32 + li) * 128 + c0 * 8];
          bf16x8 b1 = *(const bf16x8*)&sK[cur][(hhalf * 32 + 16 + li) * 128 + c0 * 8];
          s0v = mfma16(qf[grp][kd], b0, s0v);
          s1v = mfma16(qf[grp][kd], b1, s1v);
        }
        bool interior = (pkl <= pmin[grp]) && (pmax[grp] - pkf <= WINDOW);
        if (interior) {
          #pragma unroll
          for (int j = 0; j < 4; ++j) {
            float p0 = __expf(s0v[j] * scale);
            float p1 = __expf(s1v[j] * scale);
            lsum[grp][j] += p0 + p1;
            sP[w][(g * 4 + j) * 40 + li]      = (bf16)p0;
            sP[w][(g * 4 + j) * 40 + 16 + li] = (bf16)p1;
          }
        } else {
          #pragma unroll
          for (int j = 0; j < 4; ++j) {
            int d0 = pq[grp][j] - pk0, d1 = pq[grp][j] - pk1;
            float p0 = (d0 >= 0 && d0 <= WINDOW) ? __expf(s0v[j] * scale) : 0.f;
            float p1 = (d1 >= 0 && d1 <= WINDOW) ? __expf(s1v[j] * scale) : 0.f;
            lsum[grp][j] += p0 + p1;
            sP[w][(g * 4 + j) * 40 + li]      = (bf16)p0;
            sP[w][(g * 4 + j) * 40 + 16 + li] = (bf16)p1;
          }
        }
        bf16x8 pa = *(const bf16x8*)&sP[w][li * 40 + g8];
        #pragma unroll
        for (int dt = 0; dt < 8; ++dt) {
          int d = dt * 16 + li;
          int vc2 = (hhalf * 4 + g) ^ (d & 7);
          bf16x8 vf = *(const bf16x8*)&sV[cur][d * 64 + vc2 * 8];
          acc[grp][dt] = mfma16(pa, vf, acc[grp][dt]);
        }
      }
    }
  }
#undef STAGE
#undef VMW

  #pragma unroll
  for (int grp = 0; grp < 2; ++grp)
    #pragma unroll
    for (int j = 0; j < 4; ++j) {
      float rs = lsum[grp][j];
      rs += __shfl_xor(rs, 1);
      rs += __shfl_xor(rs, 2);
      rs += __shfl_xor(rs, 4);
      rs += __shfl_xor(rs, 8);
      float invl = 1.0f / rs;
      size_t base = (size_t)(rb0 + grp * 16 + g * 4 + j) * HIDDEN + h * HD;
      #pragma unroll
      for (int dt = 0; dt < 8; ++dt)
        O[base + dt * 16 + li] = (bf16)(acc[grp][dt][j] * invl);
    }
}

// ---------------- launcher --------------------------------------------------
extern "C" void kernel_launch(void* const* d_in, const int* in_sizes, int n_in,
                              void* d_out, int out_size, void* d_ws, size_t ws_size,
                              hipStream_t stream) {
  const float* X  = (const float*)d_in[0];
  const float* qw = (const float*)d_in[1];
  const float* kw = (const float*)d_in[2];
  const float* vw = (const float*)d_in[3];
  const float* ow = (const float*)d_in[4];
  const int* pos = (const int*)d_in[5];
  const int* cu  = (const int*)d_in[6];
  int T = in_sizes[0] / HIDDEN;     // 8192
  int B = in_sizes[6] - 1;          // 4
  float* out = (float*)d_out;

  bf16* ws = (bf16*)d_ws;
  size_t off = 0;
  bf16* Xb    = ws + off; off += (size_t)T * HIDDEN;
  bf16* Qb    = ws + off; off += (size_t)T * HIDDEN;       // Q, then attn out
  bf16* Kb    = ws + off; off += (size_t)T * (NKV * HD);
  bf16* Vt    = ws + off; off += (size_t)T * (NKV * HD);
  bf16* qwT   = ws + off; off += (size_t)HIDDEN * HIDDEN;
  bf16* kvwT  = ws + off; off += (size_t)1024 * HIDDEN;    // [kwT; vwT] stacked
  bf16* owT   = ws + off; off += (size_t)HIDDEN * HIDDEN;

  cast_f32_bf16<<<(T * HIDDEN / 4 + 255) / 256, 256, 0, stream>>>(X, Xb, T * HIDDEN / 4);

  dim3 tb(32, 8);
  transpose_cast<<<dim3(HIDDEN / 32, HIDDEN / 32), tb, 0, stream>>>(qw, qwT, HIDDEN, HIDDEN);
  transpose_cast<<<dim3(512 / 32, HIDDEN / 32), tb, 0, stream>>>(kw, kvwT, HIDDEN, 512);
  transpose_cast<<<dim3(512 / 32, HIDDEN / 32), tb, 0, stream>>>(vw, kvwT + (size_t)512 * HIDDEN, HIDDEN, 512);
  transpose_cast<<<dim3(HIDDEN / 32, HIDDEN / 32), tb, 0, stream>>>(ow, owT, HIDDEN, HIDDEN);

  // Q-projection (bf16 out), grid 256
  gemm256<<<(T / 256) * (HIDDEN / 256), 512, 0, stream>>>(Xb, qwT, Qb, T, HIDDEN, HIDDEN, 0);
  // merged K+V projection: 512 blocks, XCD-grouped, split epilogue
  gemm_bt<<<(T / 128) * (1024 / 128), 256, 0, stream>>>(Xb, kvwT, Kb, Vt, T, 1024, HIDDEN, 3);

  // fused RoPE (Q + K in one launch)
  rope_both<<<(T * (NHEADS + NKV) * 64 + 255) / 256, 256, 0, stream>>>(Qb, Kb, pos, T);

  // attention: 4 heads per block, KVBLK=64, grid (T/64)*NKV = 512
  attn_kernel<<<(T / 64) * NKV, 512, 0, stream>>>(Qb, Kb, Vt, pos, cu, Qb, T, B);

  // O-projection (fp32 out), grid 256
  gemm256<<<(T / 256) * (HIDDEN / 256), 512, 0, stream>>>(Qb, owT, out, T, HIDDEN, HIDDEN, 2);
}